// Round 8
// baseline (675.834 us; speedup 1.0000x reference)
//
#include <hip/hip_runtime.h>
#include <hip/hip_bf16.h>

// EquivariantBlock — Round 17 (= R16 resubmit; container infra failure, no signal).
// R15: edge1 140us, VALU 64 / Mfma 6 / occ 60. GEMM3 + m1-LDS round-trip is
// removable overhead: We2 commutes with the segment-sum (linearity fold #3):
//   agg[r] = (SUM att*silu(m1))@We2 + (SUM att)*be2.
// R16/R17: edge1 computes s1 = SUM att*silu(m1) (m1-silu kept as 16 packed-f16
// regs across the att sync; scaled+summed f32 in the existing two-pass overlay)
// and satt = SUM att; node2 applies We2 at N-scale (+1 K-loop, 32x less work)
// and adds satt*be2 rank-1. edge1 loses GEMM3 MFMA stalls, m1 f16 LDS writes,
// pack + be2 streams. s1 f16-rounds once before We2 (same class as old f16 m1).

#define D 128
#define RS 136          // LDS row stride (fp16 units or f32 overlay cols; 16B-aligned rows)

typedef unsigned short ushort;
typedef __fp16 half8 __attribute__((ext_vector_type(8)));     // MFMA operand (V8h)
typedef __fp16 h16x2 __attribute__((ext_vector_type(2)));     // builtin boundary
typedef _Float16 f16x2 __attribute__((ext_vector_type(2)));   // packed math
typedef __attribute__((ext_vector_type(4))) float f32x4;

__device__ __forceinline__ float rcpf(float x) { return __builtin_amdgcn_rcpf(x); }
__device__ __forceinline__ float siluf(float x) { return x * rcpf(1.0f + __expf(-x)); }
__device__ __forceinline__ float sigmf(float x) { return rcpf(1.0f + __expf(-x)); }
__device__ __forceinline__ ushort f2hs(float f) {
    _Float16 h = (_Float16)f; ushort u; __builtin_memcpy(&u, &h, 2); return u;
}
__device__ __forceinline__ unsigned pkh(float lo, float hi) {
    auto h = __builtin_amdgcn_cvt_pkrtz(lo, hi);   // v_cvt_pkrtz_f16_f32
    unsigned u; __builtin_memcpy(&u, &h, 4); return u;
}
__device__ __forceinline__ unsigned pkadd(unsigned a, unsigned b) {  // packed f16 a+b
    f16x2 x, y; __builtin_memcpy(&x, &a, 4); __builtin_memcpy(&y, &b, 4);
    f16x2 d = x + y; unsigned r; __builtin_memcpy(&r, &d, 4); return r;
}
__device__ __forceinline__ float2 up2(unsigned u) {  // 2 f16 -> 2 f32
    f16x2 h; __builtin_memcpy(&h, &u, 4);
    return make_float2((float)h.x, (float)h.y);
}
__device__ __forceinline__ float fdot2f(f16x2 a, f16x2 b, float c) {
#if __has_builtin(__builtin_amdgcn_fdot2)
    h16x2 ah, bh;
    __builtin_memcpy(&ah, &a, 4); __builtin_memcpy(&bh, &b, 4);
    return __builtin_amdgcn_fdot2(ah, bh, c, false);
#else
    return c + (float)a.x * (float)b.x + (float)a.y * (float)b.y;
#endif
}
#define MFMA16(a, b, c) __builtin_amdgcn_mfma_f32_16x16x32_f16((a), (b), (c), 0, 0, 0)

// packed-weight block offsets (units of 4096 ushorts)
#define PWLIN 0     // W_lin + ext(b_lin)            [5]
#define PU    5     // Wa1[0:128]  (V' = hh@W1+ba1)  [4]
#define PV    9     // Wa1[128:256]                  [4]
#define PM    13    // We1[0:128]                    [4]
#define PE2   17    // We2                           [4]
#define PN1   21    // Wn1 + ext(bn1)                [5]
#define PN2   26    // Wn2                           [4]
#define PP    30    // Wc1[0:128]                    [4]
#define PQ    34    // Wc1[128:256]                  [4]
#define PC2   38    // Wc2                           [4]
#define NPACK 42

// ---------------- zero scratch ----------------
__global__ void k_zero(float* __restrict__ p, long n) {
    long i = (long)blockIdx.x * blockDim.x + threadIdx.x;
    long stride = (long)gridDim.x * blockDim.x;
    for (; i < n; i += stride) p[i] = 0.0f;
}

// ---------------- CSR build ----------------
__global__ void k_hist(const int* __restrict__ eidx, int* __restrict__ cnt, int E) {
    int i = blockIdx.x * blockDim.x + threadIdx.x;
    const int stride = gridDim.x * blockDim.x;
    for (; i < E; i += stride) atomicAdd(&cnt[eidx[i]], 1);
}

__global__ __launch_bounds__(1024) void k_scan(const int* __restrict__ cnt,
                                               int* __restrict__ cur, int N) {
    __shared__ int part[1024];
    const int t = threadIdx.x;
    const int chunk = (N + 1023) / 1024;
    int s = 0;
    for (int k = 0; k < chunk; ++k) {
        const int i = t * chunk + k;
        if (i < N) s += cnt[i];
    }
    part[t] = s;
    __syncthreads();
    for (int d = 1; d < 1024; d <<= 1) {
        const int v = (t >= d) ? part[t - d] : 0;
        __syncthreads();
        part[t] += v;
        __syncthreads();
    }
    int base = (t == 0) ? 0 : part[t - 1];
    for (int k = 0; k < chunk; ++k) {
        const int i = t * chunk + k;
        if (i < N) { cur[i] = base; base += cnt[i]; }
    }
}

// scatter + build CSR-ordered 32B AoS records: {r,c,dist,attr | em,cdx,cdy,cdz}
__global__ void k_scatter_build(
    const int* __restrict__ eidx, const float* __restrict__ x,
    const float* __restrict__ eattr, const float* __restrict__ emask,
    int* __restrict__ cur, float4* __restrict__ rec, int E) {
    int i = blockIdx.x * blockDim.x + threadIdx.x;
    const int stride = gridDim.x * blockDim.x;
    for (; i < E; i += stride) {
        const int r = eidx[i], c = eidx[E + i];
        const int p = atomicAdd(&cur[r], 1);
        const float dx = x[r * 3 + 0] - x[c * 3 + 0];
        const float dy = x[r * 3 + 1] - x[c * 3 + 1];
        const float dz = x[r * 3 + 2] - x[c * 3 + 2];
        const float dist = sqrtf(dx * dx + dy * dy + dz * dz + 1e-8f);
        const float inv = rcpf(dist + 1.0f);
        rec[2 * p + 0] = make_float4(__int_as_float(r), __int_as_float(c), dist, eattr[i]);
        rec[2 * p + 1] = make_float4(emask[i], dx * inv, dy * inv, dz * inv);
    }
}

// ---------------- fused weight pack (fp16) ----------------
__global__ __launch_bounds__(256) void k_packall(
    const float* __restrict__ W_lin, const float* __restrict__ b_lin,
    const float* __restrict__ Wa1,
    const float* __restrict__ We1,
    const float* __restrict__ We2,
    const float* __restrict__ Wn1, const float* __restrict__ bn1,
    const float* __restrict__ Wn2,
    const float* __restrict__ Wc1,
    const float* __restrict__ Wc2,
    ushort* __restrict__ pack) {
    const int b = blockIdx.x, t = threadIdx.x;
    const float* W = nullptr; const float* bias = nullptr;
    int kbase = 0, fold = 0, ext = 0, nW = 0;
    if (b < 5)       { W = W_lin; bias = b_lin; if (b == 4) { ext = 1; nW = 0; } else kbase = b * 32; }
    else if (b < 9)  { W = Wa1; kbase = (b - 5) * 32; }                    // PU (top half)
    else if (b < 13) { W = Wa1; kbase = 128 + (b - 9) * 32; }              // PV
    else if (b < 17) { W = We1; kbase = (b - 13) * 32; }                   // PM
    else if (b < 21) { W = We2; kbase = (b - 17) * 32; }                   // PE2
    else if (b < 26) { int k = b - 21; W = Wn1; bias = bn1; if (k == 4) { ext = 1; nW = 0; } else kbase = k * 32; }
    else if (b < 30) { W = Wn2; kbase = (b - 26) * 32; }                   // PN2
    else if (b < 34) { W = Wc1; kbase = (b - 30) * 32; }                   // PP
    else if (b < 38) { W = Wc1; kbase = 128 + (b - 34) * 32; }             // PQ
    else             { W = Wc2; kbase = (b - 38) * 32; }                   // PC2
    ushort* dst = pack + (size_t)b * 4096;
#pragma unroll
    for (int i = 0; i < 16; ++i) {
        const int e = t + 256 * i;
        const int j = e & 7, lane = (e >> 3) & 63, nt = e >> 9;
        const int kl = (lane >> 4) * 8 + j;
        const int n = nt * 16 + (lane & 15);
        float v;
        if (!ext) {
            v = W[(kbase + kl) * D + n];
            if (fold) v += W[(kbase + kl + 128) * D + n];
        } else {
            v = (kl < nW) ? W[(kbase + kl) * D + n] : (kl == nW ? bias[n] : 0.0f);
        }
        dst[e] = f2hs(v);
    }
}

// ---------------- node_lin: hh = h @ W_lin + b; V',V,M',M per-node precompute ----------------
__global__ __launch_bounds__(256) void k_node_lin(
    const float* __restrict__ h, const ushort* __restrict__ pack,
    float* __restrict__ hh, ushort* __restrict__ hh1b,
    ushort* __restrict__ Vp, ushort* __restrict__ Vh,
    ushort* __restrict__ Mp, ushort* __restrict__ Mh,
    const float* __restrict__ ba1f, const float* __restrict__ be1f, int N) {
    __shared__ ushort hs[64][RS];
    const int t = threadIdx.x, lane = t & 63, wave = t >> 6;
    const int quad = lane >> 4, l16 = lane & 15;
    const int mh = wave >> 1, nh = wave & 1;
    const int base = blockIdx.x * 64;

#pragma unroll
    for (int q = 0; q < 8; ++q) {
        const int f = t + 256 * q;
        const int row = f >> 5, c4 = (f & 31) << 2;
        const int node = base + row;
        float4 v = make_float4(0.f, 0.f, 0.f, 0.f);
        if (node < N) v = *(const float4*)(h + (size_t)node * D + c4);
        *(uint2*)&hs[row][c4] = make_uint2(pkh(v.x, v.y), pkh(v.z, v.w));
    }
    float ba1v[4], be1v[4];
#pragma unroll
    for (int nt = 0; nt < 4; ++nt) {
        const int col = nh * 64 + nt * 16 + l16;
        ba1v[nt] = ba1f[col]; be1v[nt] = be1f[col];
    }
    __syncthreads();

    half8 aext = (half8)0;
    if (quad == 0) aext[0] = (__fp16)1.0f;

    f32x4 acc[2][4] = {};
    {
        const half8* pB = (const half8*)(pack + (size_t)PWLIN * 4096);
#pragma unroll
        for (int ks = 0; ks < 5; ++ks) {
            half8 bfr[4];
#pragma unroll
            for (int nt = 0; nt < 4; ++nt) bfr[nt] = pB[(ks * 8 + nh * 4 + nt) * 64 + lane];
#pragma unroll
            for (int mt = 0; mt < 2; ++mt) {
                const half8 a = (ks < 4) ? *(const half8*)&hs[mh * 32 + mt * 16 + l16][ks * 32 + quad * 8]
                                         : aext;
#pragma unroll
                for (int nt = 0; nt < 4; ++nt) acc[mt][nt] = MFMA16(a, bfr[nt], acc[mt][nt]);
            }
        }
    }
    __syncthreads();   // all hs reads done before overwrite
    // store hh (f32 out + f16) and overwrite hs with hh f16 for the precompute K-loops
#pragma unroll
    for (int mt = 0; mt < 2; ++mt)
#pragma unroll
        for (int reg = 0; reg < 4; ++reg) {
            const int row = mh * 32 + mt * 16 + quad * 4 + reg;
            const int g = base + row;
#pragma unroll
            for (int nt = 0; nt < 4; ++nt) {
                const int col = nh * 64 + nt * 16 + l16;
                const float v = acc[mt][nt][reg];
                const ushort hv = f2hs(v);
                hs[row][col] = hv;
                if (g < N) {
                    hh[(size_t)g * D + col] = v;
                    hh1b[(size_t)g * D + col] = hv;
                }
            }
        }
    __syncthreads();

    // V' = hh@Wa1_top + ba1 (f16)
    {
        f32x4 a2[2][4] = {};
        const half8* pB = (const half8*)(pack + (size_t)PU * 4096);
#pragma unroll
        for (int ks = 0; ks < 4; ++ks) {
            half8 bfr[4];
#pragma unroll
            for (int nt = 0; nt < 4; ++nt) bfr[nt] = pB[(ks * 8 + nh * 4 + nt) * 64 + lane];
#pragma unroll
            for (int mt = 0; mt < 2; ++mt) {
                const half8 a = *(const half8*)&hs[mh * 32 + mt * 16 + l16][ks * 32 + quad * 8];
#pragma unroll
                for (int nt = 0; nt < 4; ++nt) a2[mt][nt] = MFMA16(a, bfr[nt], a2[mt][nt]);
            }
        }
#pragma unroll
        for (int mt = 0; mt < 2; ++mt)
#pragma unroll
            for (int reg = 0; reg < 4; ++reg) {
                const int g = base + mh * 32 + mt * 16 + quad * 4 + reg;
                if (g < N)
#pragma unroll
                    for (int nt = 0; nt < 4; ++nt)
                        Vp[(size_t)g * D + nh * 64 + nt * 16 + l16] = f2hs(a2[mt][nt][reg] + ba1v[nt]);
            }
    }
    // V = hh@Wa1_bot (f16)
    {
        f32x4 a2[2][4] = {};
        const half8* pB = (const half8*)(pack + (size_t)PV * 4096);
#pragma unroll
        for (int ks = 0; ks < 4; ++ks) {
            half8 bfr[4];
#pragma unroll
            for (int nt = 0; nt < 4; ++nt) bfr[nt] = pB[(ks * 8 + nh * 4 + nt) * 64 + lane];
#pragma unroll
            for (int mt = 0; mt < 2; ++mt) {
                const half8 a = *(const half8*)&hs[mh * 32 + mt * 16 + l16][ks * 32 + quad * 8];
#pragma unroll
                for (int nt = 0; nt < 4; ++nt) a2[mt][nt] = MFMA16(a, bfr[nt], a2[mt][nt]);
            }
        }
#pragma unroll
        for (int mt = 0; mt < 2; ++mt)
#pragma unroll
            for (int reg = 0; reg < 4; ++reg) {
                const int g = base + mh * 32 + mt * 16 + quad * 4 + reg;
                if (g < N)
#pragma unroll
                    for (int nt = 0; nt < 4; ++nt)
                        Vh[(size_t)g * D + nh * 64 + nt * 16 + l16] = f2hs(a2[mt][nt][reg]);
            }
    }
    // M = hh@We1_top (f16); M' = be1 - M (f16)
    {
        f32x4 a2[2][4] = {};
        const half8* pB = (const half8*)(pack + (size_t)PM * 4096);
#pragma unroll
        for (int ks = 0; ks < 4; ++ks) {
            half8 bfr[4];
#pragma unroll
            for (int nt = 0; nt < 4; ++nt) bfr[nt] = pB[(ks * 8 + nh * 4 + nt) * 64 + lane];
#pragma unroll
            for (int mt = 0; mt < 2; ++mt) {
                const half8 a = *(const half8*)&hs[mh * 32 + mt * 16 + l16][ks * 32 + quad * 8];
#pragma unroll
                for (int nt = 0; nt < 4; ++nt) a2[mt][nt] = MFMA16(a, bfr[nt], a2[mt][nt]);
            }
        }
#pragma unroll
        for (int mt = 0; mt < 2; ++mt)
#pragma unroll
            for (int reg = 0; reg < 4; ++reg) {
                const int g = base + mh * 32 + mt * 16 + quad * 4 + reg;
                if (g < N)
#pragma unroll
                    for (int nt = 0; nt < 4; ++nt) {
                        const int col = nh * 64 + nt * 16 + l16;
                        const float v = a2[mt][nt][reg];
                        Mh[(size_t)g * D + col] = f2hs(v);
                        Mp[(size_t)g * D + col] = f2hs(be1v[nt] - v);
                    }
            }
    }
}

// ---------------- edge phase 1: assemble a1/m1, s1 = SUM att*silu(m1), satt ----------------
__global__ __launch_bounds__(256, 6) void k_edge1(
    const float4* __restrict__ rec,
    const ushort* __restrict__ hh1b,
    const ushort* __restrict__ Vp, const ushort* __restrict__ Vh,
    const ushort* __restrict__ Mp, const ushort* __restrict__ Mh,
    const float* __restrict__ Wa1, const float* __restrict__ We1,
    const float* __restrict__ Wa2f, const float* __restrict__ ba2f,
    float* __restrict__ s1, float* __restrict__ satt,
    float* __restrict__ geo_c, int E) {
    __shared__ float msg_s[32][RS];      // 17408B f32 overlay (two-pass)
    __shared__ float ew_s[7][128];       // rows: Wa1e0..2, We1e0..2, Wa2
    __shared__ float dist_s[64], attr_s[64], geo_s[64], att_s[64], em_s[64];
    __shared__ int node_s[64], col_s[64];

    const int t = threadIdx.x;
    const int base = blockIdx.x * 64;

    if (t < 64) {
        const int i = base + t;
        int r = 0, c = 0; float dist = 0.f, at = 0.f, emv = 0.f;
        if (i < E) {
            const float4 ra = rec[2 * i + 0];
            const float4 rb = rec[2 * i + 1];
            r = __float_as_int(ra.x); c = __float_as_int(ra.y);
            dist = ra.z; at = ra.w; emv = rb.x;
        }
        node_s[t] = r; col_s[t] = c;
        dist_s[t] = dist; attr_s[t] = at; em_s[t] = emv;
    }
    // ext-weight preload: 7 x 128 f32 (Wa1 ext rows, We1 ext rows, Wa2)
    for (int i = t; i < 896; i += 256) {
        const int r = i >> 7, c = i & 127;
        float v;
        if (r < 3)      v = Wa1[(256 + r) * D + c];
        else if (r < 6) v = We1[(128 + (r - 3)) * D + c];
        else            v = Wa2f[c];
        ew_s[r][c] = v;
    }
    __syncthreads();

    // geo = ||hh1[r] - hh1[c]|| via packed f16 diff + fdot2
    {
        const int l16 = t & 15;
        const int g = t >> 4;
#pragma unroll
        for (int it = 0; it < 4; ++it) {
            const int e = g * 4 + it;
            const uint4 vr = *(const uint4*)(hh1b + (size_t)node_s[e] * D + l16 * 8);
            const uint4 vc = *(const uint4*)(hh1b + (size_t)col_s[e] * D + l16 * 8);
            const unsigned* pr = (const unsigned*)&vr;
            const unsigned* pc = (const unsigned*)&vc;
            float s = 0.f;
#pragma unroll
            for (int q = 0; q < 4; ++q) {
                f16x2 hr2, hc2;
                __builtin_memcpy(&hr2, &pr[q], 4);
                __builtin_memcpy(&hc2, &pc[q], 4);
                const f16x2 d2 = hc2 - hr2;
                s = fdot2f(d2, d2, s);
            }
            s += __shfl_xor(s, 1); s += __shfl_xor(s, 2); s += __shfl_xor(s, 4); s += __shfl_xor(s, 8);
            if (l16 == 0) {
                const float gg = sqrtf(s + 1e-8f);
                geo_s[e] = gg;
                if (base + e < E) geo_c[base + e] = gg;
            }
        }
    }
    __syncthreads();

    // assembly: thread -> row = t>>2, col block = (t&3)*32
    // a1 = V'[r]+V[c]+ext3 (att partial) ; m1 = M'[r]+M[c]+ext3, silu kept in regs
    unsigned msil[16];
    const int row = t >> 2, cq = t & 3;
    {
        const int nr = node_s[row], nc = col_s[row];
        const float dist = dist_s[row], attr = attr_s[row], geo = geo_s[row];
        const ushort* pVr = Vp + (size_t)nr * D + cq * 32;
        const ushort* pVc = Vh + (size_t)nc * D + cq * 32;
        const ushort* pMr = Mp + (size_t)nr * D + cq * 32;
        const ushort* pMc = Mh + (size_t)nc * D + cq * 32;
        float p = 0.f;
#pragma unroll
        for (int k4 = 0; k4 < 8; ++k4) {
            const int c4 = cq * 32 + k4 * 4;
            const uint2 vru = *(const uint2*)(pVr + k4 * 4);
            const uint2 vcu = *(const uint2*)(pVc + k4 * 4);
            const uint2 mru = *(const uint2*)(pMr + k4 * 4);
            const uint2 mcu = *(const uint2*)(pMc + k4 * 4);
            const float2 av01 = up2(pkadd(vru.x, vcu.x));
            const float2 av23 = up2(pkadd(vru.y, vcu.y));
            const float2 mv01 = up2(pkadd(mru.x, mcu.x));
            const float2 mv23 = up2(pkadd(mru.y, mcu.y));
            const float4 e0 = *(const float4*)&ew_s[0][c4];
            const float4 e1 = *(const float4*)&ew_s[1][c4];
            const float4 e2 = *(const float4*)&ew_s[2][c4];
            const float4 f0 = *(const float4*)&ew_s[3][c4];
            const float4 f1 = *(const float4*)&ew_s[4][c4];
            const float4 f2 = *(const float4*)&ew_s[5][c4];
            const float4 w2 = *(const float4*)&ew_s[6][c4];
            const float a0 = av01.x + dist * e0.x + attr * e1.x + geo * e2.x;
            const float a1 = av01.y + dist * e0.y + attr * e1.y + geo * e2.y;
            const float a2 = av23.x + dist * e0.z + attr * e1.z + geo * e2.z;
            const float a3 = av23.y + dist * e0.w + attr * e1.w + geo * e2.w;
            p += siluf(a0) * w2.x + siluf(a1) * w2.y + siluf(a2) * w2.z + siluf(a3) * w2.w;
            const float m0 = siluf(mv01.x + dist * f0.x + attr * f1.x + geo * f2.x);
            const float m1v = siluf(mv01.y + dist * f0.y + attr * f1.y + geo * f2.y);
            const float m2 = siluf(mv23.x + dist * f0.z + attr * f1.z + geo * f2.z);
            const float m3 = siluf(mv23.y + dist * f0.w + attr * f1.w + geo * f2.w);
            msil[k4 * 2 + 0] = pkh(m0, m1v);
            msil[k4 * 2 + 1] = pkh(m2, m3);
        }
        p += __shfl_xor(p, 1); p += __shfl_xor(p, 2);
        if (cq == 0) att_s[row] = sigmf(p + ba2f[0]) * em_s[row];
    }
    __syncthreads();   // att ready

    // satt[r] += att (per-edge atomic; CSR-sorted -> few distinct targets)
    if (t < 64 && base + t < E) atomicAdd(&satt[node_s[t]], att_s[t]);

    // two passes: rows 0-31 then 32-63; scale msil by att, reduce into s1
#pragma unroll
    for (int pass = 0; pass < 2; ++pass) {
        if ((row >> 5) == pass) {
            const float av = att_s[row];
            const int lr = row & 31;
#pragma unroll
            for (int k4 = 0; k4 < 8; ++k4) {
                const int c4 = cq * 32 + k4 * 4;
                const float2 m01 = up2(msil[k4 * 2 + 0]);
                const float2 m23 = up2(msil[k4 * 2 + 1]);
                *(float4*)&msg_s[lr][c4] =
                    make_float4(m01.x * av, m01.y * av, m23.x * av, m23.y * av);
            }
        }
        __syncthreads();
        {
            const int j = t & 127, s = t >> 7;
            const int r0 = pass * 32 + s * 16;
            float acc = 0.f;
            int rprev = node_s[r0];
#pragma unroll
            for (int k = 0; k < 16; ++k) {
                const int rn = node_s[r0 + k];
                if (rn != rprev) {
                    atomicAdd(&s1[(size_t)rprev * D + j], acc);
                    acc = 0.f; rprev = rn;
                }
                acc += msg_s[s * 16 + k][j];
            }
            atomicAdd(&s1[(size_t)rprev * D + j], acc);
        }
        __syncthreads();
    }
}

// ---------------- node2: agg = s1@We2 + satt*be2; MLP + residual + LN + silu; P,Q ----------------
__global__ __launch_bounds__(256) void k_node2(
    const float* __restrict__ s1, const float* __restrict__ satt,
    float* hio,
    const ushort* __restrict__ pack,
    const float* __restrict__ be2f,
    const float* __restrict__ bn2f,
    const float* __restrict__ ln_g, const float* __restrict__ ln_b,
    const float* __restrict__ bc1f,
    ushort* __restrict__ Ph, ushort* __restrict__ Qh, int N) {
    __shared__ ushort ag_s[64][RS];
    __shared__ float redS[2][64], redQ[2][64];
    const int t = threadIdx.x, lane = t & 63, wave = t >> 6;
    const int quad = lane >> 4, l16 = lane & 15;
    const int mh = wave >> 1, nh = wave & 1;
    const int base = blockIdx.x * 64;

#pragma unroll
    for (int q = 0; q < 8; ++q) {
        const int f = t + 256 * q;
        const int row = f >> 5, c4 = (f & 31) << 2;
        const int node = base + row;
        float4 v = make_float4(0.f, 0.f, 0.f, 0.f);
        if (node < N) v = *(const float4*)(s1 + (size_t)node * D + c4);
        *(uint2*)&ag_s[row][c4] = make_uint2(pkh(v.x, v.y), pkh(v.z, v.w));
    }
    float bn2[4], lg[4], lb[4], bc1v[4], be2v[4];
#pragma unroll
    for (int nt = 0; nt < 4; ++nt) {
        const int col = nh * 64 + nt * 16 + l16;
        bn2[nt] = bn2f[col]; lg[nt] = ln_g[col]; lb[nt] = ln_b[col];
        bc1v[nt] = bc1f[col]; be2v[nt] = be2f[col];
    }
    __syncthreads();

    half8 aext = (half8)0;
    if (quad == 0) aext[0] = (__fp16)1.0f;

    // agg = s1@We2 + satt*be2
    f32x4 acc[2][4] = {};
    {
        const half8* pB = (const half8*)(pack + (size_t)PE2 * 4096);
#pragma unroll
        for (int ks = 0; ks < 4; ++ks) {
            half8 bfr[4];
#pragma unroll
            for (int nt = 0; nt < 4; ++nt) bfr[nt] = pB[(ks * 8 + nh * 4 + nt) * 64 + lane];
#pragma unroll
            for (int mt = 0; mt < 2; ++mt) {
                const half8 a = *(const half8*)&ag_s[mh * 32 + mt * 16 + l16][ks * 32 + quad * 8];
#pragma unroll
                for (int nt = 0; nt < 4; ++nt) acc[mt][nt] = MFMA16(a, bfr[nt], acc[mt][nt]);
            }
        }
    }
    __syncthreads();   // ag_s (s1) reads done
#pragma unroll
    for (int mt = 0; mt < 2; ++mt)
#pragma unroll
        for (int reg = 0; reg < 4; ++reg) {
            const int row = mh * 32 + mt * 16 + quad * 4 + reg;
            const int g = base + row;
            const float sa = (g < N) ? satt[g] : 0.f;
#pragma unroll
            for (int nt = 0; nt < 4; ++nt) {
                const float v = acc[mt][nt][reg] + sa * be2v[nt];
                ag_s[row][nh * 64 + nt * 16 + l16] = f2hs(v);   // agg f16 tile
            }
        }
    __syncthreads();

    // hh_mlp layer 1: silu(agg@Wn1 + bn1)
    {
        const half8* pB = (const half8*)(pack + (size_t)PN1 * 4096);
#pragma unroll
        for (int mt = 0; mt < 2; ++mt)
#pragma unroll
            for (int nt = 0; nt < 4; ++nt) acc[mt][nt] = (f32x4)0.0f;
#pragma unroll
        for (int ks = 0; ks < 5; ++ks) {
            half8 bfr[4];
#pragma unroll
            for (int nt = 0; nt < 4; ++nt) bfr[nt] = pB[(ks * 8 + nh * 4 + nt) * 64 + lane];
#pragma unroll
            for (int mt = 0; mt < 2; ++mt) {
                const half8 a = (ks < 4) ? *(const half8*)&ag_s[mh * 32 + mt * 16 + l16][ks * 32 + quad * 8]
                                         : aext;
#pragma unroll
                for (int nt = 0; nt < 4; ++nt) acc[mt][nt] = MFMA16(a, bfr[nt], acc[mt][nt]);
            }
        }
    }
    __syncthreads();
#pragma unroll
    for (int mt = 0; mt < 2; ++mt)
#pragma unroll
        for (int reg = 0; reg < 4; ++reg) {
            const int row = mh * 32 + mt * 16 + quad * 4 + reg;
#pragma unroll
            for (int nt = 0; nt < 4; ++nt)
                ag_s[row][nh * 64 + nt * 16 + l16] = f2hs(siluf(acc[mt][nt][reg]));
        }
    __syncthreads();

    {
        const half8* pB = (const half8*)(pack + (size_t)PN2 * 4096);
#pragma unroll
        for (int mt = 0; mt < 2; ++mt)
#pragma unroll
            for (int nt = 0; nt < 4; ++nt) acc[mt][nt] = (f32x4)0.0f;
#pragma unroll
        for (int ks = 0; ks < 4; ++ks) {
            half8 bfr[4];
#pragma unroll
            for (int nt = 0; nt < 4; ++nt) bfr[nt] = pB[(ks * 8 + nh * 4 + nt) * 64 + lane];
#pragma unroll
            for (int mt = 0; mt < 2; ++mt) {
                const half8 a = *(const half8*)&ag_s[mh * 32 + mt * 16 + l16][ks * 32 + quad * 8];
#pragma unroll
                for (int nt = 0; nt < 4; ++nt) acc[mt][nt] = MFMA16(a, bfr[nt], acc[mt][nt]);
            }
        }
    }
#pragma unroll
    for (int mt = 0; mt < 2; ++mt)
#pragma unroll
        for (int reg = 0; reg < 4; ++reg) {
            const int row = mh * 32 + mt * 16 + quad * 4 + reg;
            const int g = base + row;
            float s = 0.f, qq = 0.f;
#pragma unroll
            for (int nt = 0; nt < 4; ++nt) {
                const int col = nh * 64 + nt * 16 + l16;
                float v = acc[mt][nt][reg] + bn2[nt];
                if (g < N) v += hio[(size_t)g * D + col];
                acc[mt][nt][reg] = v;
                s += v; qq += v * v;
            }
            s += __shfl_xor(s, 1); s += __shfl_xor(s, 2); s += __shfl_xor(s, 4); s += __shfl_xor(s, 8);
            qq += __shfl_xor(qq, 1); qq += __shfl_xor(qq, 2); qq += __shfl_xor(qq, 4); qq += __shfl_xor(qq, 8);
            if (l16 == 0) { redS[nh][row] = s; redQ[nh][row] = qq; }
        }
    __syncthreads();

#pragma unroll
    for (int mt = 0; mt < 2; ++mt)
#pragma unroll
        for (int reg = 0; reg < 4; ++reg) {
            const int row = mh * 32 + mt * 16 + quad * 4 + reg;
            const int g = base + row;
            const float mu = (redS[0][row] + redS[1][row]) * (1.0f / D);
            const float var = (redQ[0][row] + redQ[1][row]) * (1.0f / D) - mu * mu;
            const float rstd = rsqrtf(var + 1e-5f);
#pragma unroll
            for (int nt = 0; nt < 4; ++nt) {
                const int col = nh * 64 + nt * 16 + l16;
                const float hn = (acc[mt][nt][reg] - mu) * rstd * lg[nt] + lb[nt];
                const float o = siluf(hn);
                ag_s[row][col] = f2hs(o);                     // hh2 f16 for P/Q K-loops
                if (g < N) hio[(size_t)g * D + col] = o;
            }
        }
    __syncthreads();

    // P = hh2@Wc1_top + bc1 (f16)
    {
        f32x4 a2[2][4] = {};
        const half8* pB = (const half8*)(pack + (size_t)PP * 4096);
#pragma unroll
        for (int ks = 0; ks < 4; ++ks) {
            half8 bfr[4];
#pragma unroll
            for (int nt = 0; nt < 4; ++nt) bfr[nt] = pB[(ks * 8 + nh * 4 + nt) * 64 + lane];
#pragma unroll
            for (int mt = 0; mt < 2; ++mt) {
                const half8 a = *(const half8*)&ag_s[mh * 32 + mt * 16 + l16][ks * 32 + quad * 8];
#pragma unroll
                for (int nt = 0; nt < 4; ++nt) a2[mt][nt] = MFMA16(a, bfr[nt], a2[mt][nt]);
            }
        }
#pragma unroll
        for (int mt = 0; mt < 2; ++mt)
#pragma unroll
            for (int reg = 0; reg < 4; ++reg) {
                const int g = base + mh * 32 + mt * 16 + quad * 4 + reg;
                if (g < N)
#pragma unroll
                    for (int nt = 0; nt < 4; ++nt)
                        Ph[(size_t)g * D + nh * 64 + nt * 16 + l16] = f2hs(a2[mt][nt][reg] + bc1v[nt]);
            }
    }
    // Q = hh2@Wc1_bot (f16)
    {
        f32x4 a2[2][4] = {};
        const half8* pB = (const half8*)(pack + (size_t)PQ * 4096);
#pragma unroll
        for (int ks = 0; ks < 4; ++ks) {
            half8 bfr[4];
#pragma unroll
            for (int nt = 0; nt < 4; ++nt) bfr[nt] = pB[(ks * 8 + nh * 4 + nt) * 64 + lane];
#pragma unroll
            for (int mt = 0; mt < 2; ++mt) {
                const half8 a = *(const half8*)&ag_s[mh * 32 + mt * 16 + l16][ks * 32 + quad * 8];
#pragma unroll
                for (int nt = 0; nt < 4; ++nt) a2[mt][nt] = MFMA16(a, bfr[nt], a2[mt][nt]);
            }
        }
#pragma unroll
        for (int mt = 0; mt < 2; ++mt)
#pragma unroll
            for (int reg = 0; reg < 4; ++reg) {
                const int g = base + mh * 32 + mt * 16 + quad * 4 + reg;
                if (g < N)
#pragma unroll
                    for (int nt = 0; nt < 4; ++nt)
                        Qh[(size_t)g * D + nh * 64 + nt * 16 + l16] = f2hs(a2[mt][nt][reg]);
            }
    }
}

// ---------------- edge phase 2: assemble c1, GEMM2, coord reduce ----------------
__global__ __launch_bounds__(256, 6) void k_edge2(
    const float4* __restrict__ rec, const float* __restrict__ geo_c,
    const ushort* __restrict__ Ph, const ushort* __restrict__ Qh,
    const ushort* __restrict__ pack,
    const float* __restrict__ Wc1,
    const float* __restrict__ bc2f, const float* __restrict__ Wc3f,
    float* __restrict__ aggx, int E) {
    __shared__ ushort c1_s[64][RS];
    __shared__ float ew_s[3][128];
    __shared__ float dist_s[64], attr_s[64], geo_s[64], tr_s[64];
    __shared__ float cdx_s[64], cdy_s[64], cdz_s[64];
    __shared__ int node_s[64], col_s[64];
    __shared__ float mp_s[4][64];

    const int t = threadIdx.x, lane = t & 63, w = t >> 6;
    const int quad = lane >> 4, l16 = lane & 15;
    const int base = blockIdx.x * 64;

    if (t < 64) {
        const int i = base + t;
        int r = 0, c = 0;
        float dist = 1.f, geo = 0.f, at = 0.f, emv = 0.f, cdx = 0.f, cdy = 0.f, cdz = 0.f;
        if (i < E) {
            const float4 ra = rec[2 * i + 0];
            const float4 rb = rec[2 * i + 1];
            r = __float_as_int(ra.x); c = __float_as_int(ra.y);
            dist = ra.z; at = ra.w;
            emv = rb.x; cdx = rb.y; cdy = rb.z; cdz = rb.w;
            geo = geo_c[i];
        }
        node_s[t] = r; col_s[t] = c;
        dist_s[t] = dist; geo_s[t] = geo; attr_s[t] = at; tr_s[t] = emv;  // tr_s holds em
        cdx_s[t] = cdx; cdy_s[t] = cdy; cdz_s[t] = cdz;
    }
    for (int i = t; i < 384; i += 256) {
        const int r = i >> 7, c = i & 127;
        ew_s[r][c] = Wc1[(256 + r) * D + c];
    }
    float bc2[2], wc3[2];
#pragma unroll
    for (int nt = 0; nt < 2; ++nt) {
        const int col = w * 32 + nt * 16 + l16;
        bc2[nt] = bc2f[col]; wc3[nt] = Wc3f[col];
    }
    __syncthreads();

    // c1 assembly: c1 = silu(P[r] + Q[c] + ext3), ext rows from LDS
    {
        const int row = t >> 2, cq = t & 3;
        const int nr = node_s[row], nc = col_s[row];
        const float dist = dist_s[row], attr = attr_s[row], geo = geo_s[row];
        const ushort* pP = Ph + (size_t)nr * D + cq * 32;
        const ushort* pQ = Qh + (size_t)nc * D + cq * 32;
#pragma unroll
        for (int k4 = 0; k4 < 8; ++k4) {
            const int c4 = cq * 32 + k4 * 4;
            const uint2 pu = *(const uint2*)(pP + k4 * 4);
            const uint2 qu = *(const uint2*)(pQ + k4 * 4);
            const float2 s01 = up2(pkadd(pu.x, qu.x));
            const float2 s23 = up2(pkadd(pu.y, qu.y));
            const float4 e0 = *(const float4*)&ew_s[0][c4];
            const float4 e1 = *(const float4*)&ew_s[1][c4];
            const float4 e2 = *(const float4*)&ew_s[2][c4];
            const float c0 = siluf(s01.x + dist * e0.x + attr * e1.x + geo * e2.x);
            const float c1 = siluf(s01.y + dist * e0.y + attr * e1.y + geo * e2.y);
            const float c2 = siluf(s23.x + dist * e0.z + attr * e1.z + geo * e2.z);
            const float c3 = siluf(s23.y + dist * e0.w + attr * e1.w + geo * e2.w);
            *(uint2*)&c1_s[row][c4] = make_uint2(pkh(c0, c1), pkh(c2, c3));
        }
    }
    __syncthreads();

    // GEMM2: c2 = silu(c1@Wc2 + bc2); m-partials over this wave's cols
    {
        f32x4 acc[4][2] = {};
        const half8* pB = (const half8*)(pack + (size_t)PC2 * 4096);
#pragma unroll
        for (int ks = 0; ks < 4; ++ks) {
            const half8 b0 = pB[(ks * 8 + w * 2 + 0) * 64 + lane];
            const half8 b1 = pB[(ks * 8 + w * 2 + 1) * 64 + lane];
#pragma unroll
            for (int mt = 0; mt < 4; ++mt) {
                const half8 a = *(const half8*)&c1_s[mt * 16 + l16][ks * 32 + quad * 8];
                acc[mt][0] = MFMA16(a, b0, acc[mt][0]);
                acc[mt][1] = MFMA16(a, b1, acc[mt][1]);
            }
        }
#pragma unroll
        for (int mt = 0; mt < 4; ++mt)
#pragma unroll
            for (int reg = 0; reg < 4; ++reg) {
                float p = siluf(acc[mt][0][reg] + bc2[0]) * wc3[0]
                        + siluf(acc[mt][1][reg] + bc2[1]) * wc3[1];
                p += __shfl_xor(p, 1); p += __shfl_xor(p, 2); p += __shfl_xor(p, 4); p += __shfl_xor(p, 8);
                if (l16 == 0) mp_s[w][mt * 16 + quad * 4 + reg] = p;
            }
    }
    __syncthreads();

    if (t < 64) {
        const float m = mp_s[0][t] + mp_s[1][t] + mp_s[2][t] + mp_s[3][t];
        tr_s[t] = m * tr_s[t];   // m * em
        if (base + t >= E) tr_s[t] = 0.f;
    }
    __syncthreads();

    // segmented per-block reduce of trans into aggx (3 lanes x,y,z; two 32-row halves)
    {
        const int h = t >> 7, tt = t & 127;
        if (tt < 3) {
            const float* cds = (tt == 0) ? cdx_s : (tt == 1) ? cdy_s : cdz_s;
            float acc = 0.f;
            int rprev = node_s[h * 32];
#pragma unroll
            for (int k = 0; k < 32; ++k) {
                const int row = h * 32 + k;
                const int rn = node_s[row];
                if (rn != rprev) {
                    atomicAdd(&aggx[rprev * 4 + tt], acc);
                    acc = 0.f; rprev = rn;
                }
                acc += cds[row] * tr_s[row];
            }
            atomicAdd(&aggx[rprev * 4 + tt], acc);
        }
    }
}

// ---------------- coord epilogue ----------------
__global__ void k_coord(const float* __restrict__ x, const float* __restrict__ nmask,
                        const float* __restrict__ aggx, float* __restrict__ out_x, int N) {
    const int idx = blockIdx.x * blockDim.x + threadIdx.x;
    if (idx >= N * 3) return;
    const int i = idx / 3, d = idx - i * 3;
    out_x[idx] = (x[idx] + aggx[i * 4 + d] * (1.0f / 100.0f)) * nmask[i];
}

extern "C" void kernel_launch(void* const* d_in, const int* in_sizes, int n_in,
                              void* d_out, int out_size, void* d_ws, size_t ws_size,
                              hipStream_t stream) {
    const float* h     = (const float*)d_in[0];
    const float* x     = (const float*)d_in[1];
    const int*   eidx  = (const int*)d_in[2];
    const float* nmask = (const float*)d_in[3];
    const float* emask = (const float*)d_in[4];
    const float* eattr = (const float*)d_in[5];
    const float* W_lin = (const float*)d_in[6];
    const float* b_lin = (const float*)d_in[7];
    const float* We1   = (const float*)d_in[8];
    const float* be1   = (const float*)d_in[9];
    const float* We2   = (const float*)d_in[10];
    const float* be2   = (const float*)d_in[11];
    const float* Wn1   = (const float*)d_in[12];
    const float* bn1   = (const float*)d_in[13];
    const float* Wn2   = (const float*)d_in[14];
    const float* bn2   = (const float*)d_in[15];
    const float* Wa1   = (const float*)d_in[16];
    const float* ba1   = (const float*)d_in[17];
    const float* Wa2   = (const float*)d_in[18];
    const float* ba2   = (const float*)d_in[19];
    const float* ln_g  = (const float*)d_in[20];
    const float* ln_b  = (const float*)d_in[21];
    const float* Wc1   = (const float*)d_in[22];
    const float* bc1   = (const float*)d_in[23];
    const float* Wc2   = (const float*)d_in[24];
    const float* bc2   = (const float*)d_in[25];
    const float* Wc3   = (const float*)d_in[26];

    const int N = in_sizes[0] / D;
    const int E = in_sizes[2] / 2;

    // ws layout (256-B aligned regions), ~60 MB
    char* wp = (char*)d_ws;
    auto take = [&](size_t bytes) -> void* {
        void* p = wp; wp += (bytes + 255) & ~(size_t)255; return p;
    };
    float*  s1    = (float*)take((size_t)N * D * 4);   // ┐ zeroed as one
    float*  aggx  = (float*)take((size_t)N * 4 * 4);   // │ contiguous
    float*  satt  = (float*)take((size_t)N * 4);       // │ region
    int*    cnt   = (int*)take((size_t)N * 4);         // ┘
    int*    cur   = (int*)take((size_t)N * 4);
    float4* rec   = (float4*)take((size_t)E * 32);
    float*  geo_c = (float*)take((size_t)E * 4);
    ushort* hh1b  = (ushort*)take((size_t)N * D * 2);
    ushort* Vp    = (ushort*)take((size_t)N * D * 2);
    ushort* Vh    = (ushort*)take((size_t)N * D * 2);
    ushort* Mp    = (ushort*)take((size_t)N * D * 2);
    ushort* Mh    = (ushort*)take((size_t)N * D * 2);
    ushort* Ph    = (ushort*)take((size_t)N * D * 2);
    ushort* Qh    = (ushort*)take((size_t)N * D * 2);
    ushort* pack  = (ushort*)take((size_t)NPACK * 4096 * 2);

    float* out_h = (float*)d_out;          // doubles as hh fp32 storage
    float* out_x = out_h + (size_t)N * D;

    const int EB = (E + 63) / 64;
    const int NB = (N + 63) / 64;
    const long zn = ((char*)(cnt + N) - (char*)s1) / 4;   // s1..cnt contiguous

    k_zero<<<2048, 256, 0, stream>>>(s1, zn);
    k_packall<<<NPACK, 256, 0, stream>>>(W_lin, b_lin, Wa1, We1, We2,
                                         Wn1, bn1, Wn2, Wc1, Wc2, pack);
    k_hist<<<1024, 256, 0, stream>>>(eidx, cnt, E);
    k_scan<<<1, 1024, 0, stream>>>(cnt, cur, N);
    k_scatter_build<<<1024, 256, 0, stream>>>(eidx, x, eattr, emask, cur, rec, E);
    k_node_lin<<<NB, 256, 0, stream>>>(h, pack, out_h, hh1b, Vp, Vh, Mp, Mh, ba1, be1, N);
    k_edge1<<<EB, 256, 0, stream>>>(rec, hh1b, Vp, Vh, Mp, Mh, Wa1, We1,
                                    Wa2, ba2, s1, satt, geo_c, E);
    k_node2<<<NB, 256, 0, stream>>>(s1, satt, out_h, pack, be2, bn2, ln_g, ln_b,
                                    bc1, Ph, Qh, N);
    k_edge2<<<EB, 256, 0, stream>>>(rec, geo_c, Ph, Qh, pack, Wc1, bc2, Wc3, aggx, E);
    k_coord<<<(N * 3 + 255) / 256, 256, 0, stream>>>(x, nmask, aggx, out_x, N);
}

// Round 9
// 544.043 us; speedup vs baseline: 1.2422x; 1.2422x over previous
//
#include <hip/hip_runtime.h>
#include <hip/hip_bf16.h>

// EquivariantBlock — Round 18.
// R17 post-mortem: keeping msil[16] packed-f16 regs live ACROSS __syncthreads
// spilled to scratch (VGPR stayed 40; WRITE 93->691MB, FETCH 243->569MB; edge1
// 140->354us, HBM-bound at 46%). Compiler won't grow VGPR for cross-barrier
// state. R18: keep the We2 linearity fold (s1 = SUM att*silu(m1), We2@node2)
// but write m1 as f16 to the LDS tile (m1_s[64][RS], the bytes GEMM3 used to
// read) + att to LDS; ONE sync; segmented reduce reads m1 f16, scales by att
// at read time, accumulates f32, atomics to s1. No overlay, no cross-barrier
// regs. LDS 23040 = 6 blk/CU, same as R15.

#define D 128
#define RS 136          // LDS row stride in fp16 units (128 + 8 pad; 272B rows)

typedef unsigned short ushort;
typedef __fp16 half8 __attribute__((ext_vector_type(8)));     // MFMA operand (V8h)
typedef __fp16 h16x2 __attribute__((ext_vector_type(2)));     // builtin boundary
typedef _Float16 f16x2 __attribute__((ext_vector_type(2)));   // packed math
typedef __attribute__((ext_vector_type(4))) float f32x4;

__device__ __forceinline__ float rcpf(float x) { return __builtin_amdgcn_rcpf(x); }
__device__ __forceinline__ float siluf(float x) { return x * rcpf(1.0f + __expf(-x)); }
__device__ __forceinline__ float sigmf(float x) { return rcpf(1.0f + __expf(-x)); }
__device__ __forceinline__ ushort f2hs(float f) {
    _Float16 h = (_Float16)f; ushort u; __builtin_memcpy(&u, &h, 2); return u;
}
__device__ __forceinline__ unsigned pkh(float lo, float hi) {
    auto h = __builtin_amdgcn_cvt_pkrtz(lo, hi);   // v_cvt_pkrtz_f16_f32
    unsigned u; __builtin_memcpy(&u, &h, 4); return u;
}
__device__ __forceinline__ unsigned pkadd(unsigned a, unsigned b) {  // packed f16 a+b
    f16x2 x, y; __builtin_memcpy(&x, &a, 4); __builtin_memcpy(&y, &b, 4);
    f16x2 d = x + y; unsigned r; __builtin_memcpy(&r, &d, 4); return r;
}
__device__ __forceinline__ float2 up2(unsigned u) {  // 2 f16 -> 2 f32
    f16x2 h; __builtin_memcpy(&h, &u, 4);
    return make_float2((float)h.x, (float)h.y);
}
__device__ __forceinline__ float fdot2f(f16x2 a, f16x2 b, float c) {
#if __has_builtin(__builtin_amdgcn_fdot2)
    h16x2 ah, bh;
    __builtin_memcpy(&ah, &a, 4); __builtin_memcpy(&bh, &b, 4);
    return __builtin_amdgcn_fdot2(ah, bh, c, false);
#else
    return c + (float)a.x * (float)b.x + (float)a.y * (float)b.y;
#endif
}
#define MFMA16(a, b, c) __builtin_amdgcn_mfma_f32_16x16x32_f16((a), (b), (c), 0, 0, 0)

// packed-weight block offsets (units of 4096 ushorts)
#define PWLIN 0     // W_lin + ext(b_lin)            [5]
#define PU    5     // Wa1[0:128]  (V' = hh@W1+ba1)  [4]
#define PV    9     // Wa1[128:256]                  [4]
#define PM    13    // We1[0:128]                    [4]
#define PE2   17    // We2                           [4]
#define PN1   21    // Wn1 + ext(bn1)                [5]
#define PN2   26    // Wn2                           [4]
#define PP    30    // Wc1[0:128]                    [4]
#define PQ    34    // Wc1[128:256]                  [4]
#define PC2   38    // Wc2                           [4]
#define NPACK 42

// ---------------- zero scratch ----------------
__global__ void k_zero(float* __restrict__ p, long n) {
    long i = (long)blockIdx.x * blockDim.x + threadIdx.x;
    long stride = (long)gridDim.x * blockDim.x;
    for (; i < n; i += stride) p[i] = 0.0f;
}

// ---------------- CSR build ----------------
__global__ void k_hist(const int* __restrict__ eidx, int* __restrict__ cnt, int E) {
    int i = blockIdx.x * blockDim.x + threadIdx.x;
    const int stride = gridDim.x * blockDim.x;
    for (; i < E; i += stride) atomicAdd(&cnt[eidx[i]], 1);
}

__global__ __launch_bounds__(1024) void k_scan(const int* __restrict__ cnt,
                                               int* __restrict__ cur, int N) {
    __shared__ int part[1024];
    const int t = threadIdx.x;
    const int chunk = (N + 1023) / 1024;
    int s = 0;
    for (int k = 0; k < chunk; ++k) {
        const int i = t * chunk + k;
        if (i < N) s += cnt[i];
    }
    part[t] = s;
    __syncthreads();
    for (int d = 1; d < 1024; d <<= 1) {
        const int v = (t >= d) ? part[t - d] : 0;
        __syncthreads();
        part[t] += v;
        __syncthreads();
    }
    int base = (t == 0) ? 0 : part[t - 1];
    for (int k = 0; k < chunk; ++k) {
        const int i = t * chunk + k;
        if (i < N) { cur[i] = base; base += cnt[i]; }
    }
}

// scatter + build CSR-ordered 32B AoS records: {r,c,dist,attr | em,cdx,cdy,cdz}
__global__ void k_scatter_build(
    const int* __restrict__ eidx, const float* __restrict__ x,
    const float* __restrict__ eattr, const float* __restrict__ emask,
    int* __restrict__ cur, float4* __restrict__ rec, int E) {
    int i = blockIdx.x * blockDim.x + threadIdx.x;
    const int stride = gridDim.x * blockDim.x;
    for (; i < E; i += stride) {
        const int r = eidx[i], c = eidx[E + i];
        const int p = atomicAdd(&cur[r], 1);
        const float dx = x[r * 3 + 0] - x[c * 3 + 0];
        const float dy = x[r * 3 + 1] - x[c * 3 + 1];
        const float dz = x[r * 3 + 2] - x[c * 3 + 2];
        const float dist = sqrtf(dx * dx + dy * dy + dz * dz + 1e-8f);
        const float inv = rcpf(dist + 1.0f);
        rec[2 * p + 0] = make_float4(__int_as_float(r), __int_as_float(c), dist, eattr[i]);
        rec[2 * p + 1] = make_float4(emask[i], dx * inv, dy * inv, dz * inv);
    }
}

// ---------------- fused weight pack (fp16) ----------------
__global__ __launch_bounds__(256) void k_packall(
    const float* __restrict__ W_lin, const float* __restrict__ b_lin,
    const float* __restrict__ Wa1,
    const float* __restrict__ We1,
    const float* __restrict__ We2,
    const float* __restrict__ Wn1, const float* __restrict__ bn1,
    const float* __restrict__ Wn2,
    const float* __restrict__ Wc1,
    const float* __restrict__ Wc2,
    ushort* __restrict__ pack) {
    const int b = blockIdx.x, t = threadIdx.x;
    const float* W = nullptr; const float* bias = nullptr;
    int kbase = 0, fold = 0, ext = 0, nW = 0;
    if (b < 5)       { W = W_lin; bias = b_lin; if (b == 4) { ext = 1; nW = 0; } else kbase = b * 32; }
    else if (b < 9)  { W = Wa1; kbase = (b - 5) * 32; }                    // PU (top half)
    else if (b < 13) { W = Wa1; kbase = 128 + (b - 9) * 32; }              // PV
    else if (b < 17) { W = We1; kbase = (b - 13) * 32; }                   // PM
    else if (b < 21) { W = We2; kbase = (b - 17) * 32; }                   // PE2
    else if (b < 26) { int k = b - 21; W = Wn1; bias = bn1; if (k == 4) { ext = 1; nW = 0; } else kbase = k * 32; }
    else if (b < 30) { W = Wn2; kbase = (b - 26) * 32; }                   // PN2
    else if (b < 34) { W = Wc1; kbase = (b - 30) * 32; }                   // PP
    else if (b < 38) { W = Wc1; kbase = 128 + (b - 34) * 32; }             // PQ
    else             { W = Wc2; kbase = (b - 38) * 32; }                   // PC2
    ushort* dst = pack + (size_t)b * 4096;
#pragma unroll
    for (int i = 0; i < 16; ++i) {
        const int e = t + 256 * i;
        const int j = e & 7, lane = (e >> 3) & 63, nt = e >> 9;
        const int kl = (lane >> 4) * 8 + j;
        const int n = nt * 16 + (lane & 15);
        float v;
        if (!ext) {
            v = W[(kbase + kl) * D + n];
            if (fold) v += W[(kbase + kl + 128) * D + n];
        } else {
            v = (kl < nW) ? W[(kbase + kl) * D + n] : (kl == nW ? bias[n] : 0.0f);
        }
        dst[e] = f2hs(v);
    }
}

// ---------------- node_lin: hh = h @ W_lin + b; V',V,M',M per-node precompute ----------------
__global__ __launch_bounds__(256) void k_node_lin(
    const float* __restrict__ h, const ushort* __restrict__ pack,
    float* __restrict__ hh, ushort* __restrict__ hh1b,
    ushort* __restrict__ Vp, ushort* __restrict__ Vh,
    ushort* __restrict__ Mp, ushort* __restrict__ Mh,
    const float* __restrict__ ba1f, const float* __restrict__ be1f, int N) {
    __shared__ ushort hs[64][RS];
    const int t = threadIdx.x, lane = t & 63, wave = t >> 6;
    const int quad = lane >> 4, l16 = lane & 15;
    const int mh = wave >> 1, nh = wave & 1;
    const int base = blockIdx.x * 64;

#pragma unroll
    for (int q = 0; q < 8; ++q) {
        const int f = t + 256 * q;
        const int row = f >> 5, c4 = (f & 31) << 2;
        const int node = base + row;
        float4 v = make_float4(0.f, 0.f, 0.f, 0.f);
        if (node < N) v = *(const float4*)(h + (size_t)node * D + c4);
        *(uint2*)&hs[row][c4] = make_uint2(pkh(v.x, v.y), pkh(v.z, v.w));
    }
    float ba1v[4], be1v[4];
#pragma unroll
    for (int nt = 0; nt < 4; ++nt) {
        const int col = nh * 64 + nt * 16 + l16;
        ba1v[nt] = ba1f[col]; be1v[nt] = be1f[col];
    }
    __syncthreads();

    half8 aext = (half8)0;
    if (quad == 0) aext[0] = (__fp16)1.0f;

    f32x4 acc[2][4] = {};
    {
        const half8* pB = (const half8*)(pack + (size_t)PWLIN * 4096);
#pragma unroll
        for (int ks = 0; ks < 5; ++ks) {
            half8 bfr[4];
#pragma unroll
            for (int nt = 0; nt < 4; ++nt) bfr[nt] = pB[(ks * 8 + nh * 4 + nt) * 64 + lane];
#pragma unroll
            for (int mt = 0; mt < 2; ++mt) {
                const half8 a = (ks < 4) ? *(const half8*)&hs[mh * 32 + mt * 16 + l16][ks * 32 + quad * 8]
                                         : aext;
#pragma unroll
                for (int nt = 0; nt < 4; ++nt) acc[mt][nt] = MFMA16(a, bfr[nt], acc[mt][nt]);
            }
        }
    }
    __syncthreads();   // all hs reads done before overwrite
    // store hh (f32 out + f16) and overwrite hs with hh f16 for the precompute K-loops
#pragma unroll
    for (int mt = 0; mt < 2; ++mt)
#pragma unroll
        for (int reg = 0; reg < 4; ++reg) {
            const int row = mh * 32 + mt * 16 + quad * 4 + reg;
            const int g = base + row;
#pragma unroll
            for (int nt = 0; nt < 4; ++nt) {
                const int col = nh * 64 + nt * 16 + l16;
                const float v = acc[mt][nt][reg];
                const ushort hv = f2hs(v);
                hs[row][col] = hv;
                if (g < N) {
                    hh[(size_t)g * D + col] = v;
                    hh1b[(size_t)g * D + col] = hv;
                }
            }
        }
    __syncthreads();

    // V' = hh@Wa1_top + ba1 (f16)
    {
        f32x4 a2[2][4] = {};
        const half8* pB = (const half8*)(pack + (size_t)PU * 4096);
#pragma unroll
        for (int ks = 0; ks < 4; ++ks) {
            half8 bfr[4];
#pragma unroll
            for (int nt = 0; nt < 4; ++nt) bfr[nt] = pB[(ks * 8 + nh * 4 + nt) * 64 + lane];
#pragma unroll
            for (int mt = 0; mt < 2; ++mt) {
                const half8 a = *(const half8*)&hs[mh * 32 + mt * 16 + l16][ks * 32 + quad * 8];
#pragma unroll
                for (int nt = 0; nt < 4; ++nt) a2[mt][nt] = MFMA16(a, bfr[nt], a2[mt][nt]);
            }
        }
#pragma unroll
        for (int mt = 0; mt < 2; ++mt)
#pragma unroll
            for (int reg = 0; reg < 4; ++reg) {
                const int g = base + mh * 32 + mt * 16 + quad * 4 + reg;
                if (g < N)
#pragma unroll
                    for (int nt = 0; nt < 4; ++nt)
                        Vp[(size_t)g * D + nh * 64 + nt * 16 + l16] = f2hs(a2[mt][nt][reg] + ba1v[nt]);
            }
    }
    // V = hh@Wa1_bot (f16)
    {
        f32x4 a2[2][4] = {};
        const half8* pB = (const half8*)(pack + (size_t)PV * 4096);
#pragma unroll
        for (int ks = 0; ks < 4; ++ks) {
            half8 bfr[4];
#pragma unroll
            for (int nt = 0; nt < 4; ++nt) bfr[nt] = pB[(ks * 8 + nh * 4 + nt) * 64 + lane];
#pragma unroll
            for (int mt = 0; mt < 2; ++mt) {
                const half8 a = *(const half8*)&hs[mh * 32 + mt * 16 + l16][ks * 32 + quad * 8];
#pragma unroll
                for (int nt = 0; nt < 4; ++nt) a2[mt][nt] = MFMA16(a, bfr[nt], a2[mt][nt]);
            }
        }
#pragma unroll
        for (int mt = 0; mt < 2; ++mt)
#pragma unroll
            for (int reg = 0; reg < 4; ++reg) {
                const int g = base + mh * 32 + mt * 16 + quad * 4 + reg;
                if (g < N)
#pragma unroll
                    for (int nt = 0; nt < 4; ++nt)
                        Vh[(size_t)g * D + nh * 64 + nt * 16 + l16] = f2hs(a2[mt][nt][reg]);
            }
    }
    // M = hh@We1_top (f16); M' = be1 - M (f16)
    {
        f32x4 a2[2][4] = {};
        const half8* pB = (const half8*)(pack + (size_t)PM * 4096);
#pragma unroll
        for (int ks = 0; ks < 4; ++ks) {
            half8 bfr[4];
#pragma unroll
            for (int nt = 0; nt < 4; ++nt) bfr[nt] = pB[(ks * 8 + nh * 4 + nt) * 64 + lane];
#pragma unroll
            for (int mt = 0; mt < 2; ++mt) {
                const half8 a = *(const half8*)&hs[mh * 32 + mt * 16 + l16][ks * 32 + quad * 8];
#pragma unroll
                for (int nt = 0; nt < 4; ++nt) a2[mt][nt] = MFMA16(a, bfr[nt], a2[mt][nt]);
            }
        }
#pragma unroll
        for (int mt = 0; mt < 2; ++mt)
#pragma unroll
            for (int reg = 0; reg < 4; ++reg) {
                const int g = base + mh * 32 + mt * 16 + quad * 4 + reg;
                if (g < N)
#pragma unroll
                    for (int nt = 0; nt < 4; ++nt) {
                        const int col = nh * 64 + nt * 16 + l16;
                        const float v = a2[mt][nt][reg];
                        Mh[(size_t)g * D + col] = f2hs(v);
                        Mp[(size_t)g * D + col] = f2hs(be1v[nt] - v);
                    }
            }
    }
}

// ---------------- edge phase 1: assemble a1/m1 (m1->LDS f16), s1 = SUM att*silu(m1), satt ----------------
__global__ __launch_bounds__(256, 6) void k_edge1(
    const float4* __restrict__ rec,
    const ushort* __restrict__ hh1b,
    const ushort* __restrict__ Vp, const ushort* __restrict__ Vh,
    const ushort* __restrict__ Mp, const ushort* __restrict__ Mh,
    const float* __restrict__ Wa1, const float* __restrict__ We1,
    const float* __restrict__ Wa2f, const float* __restrict__ ba2f,
    float* __restrict__ s1, float* __restrict__ satt,
    float* __restrict__ geo_c, int E) {
    __shared__ ushort m1_s[64][RS];      // 17408B f16 m1 tile (unscaled silu(m1))
    __shared__ float ew_s[7][128];       // rows: Wa1e0..2, We1e0..2, Wa2
    __shared__ float dist_s[64], attr_s[64], geo_s[64], att_s[64], em_s[64];
    __shared__ int node_s[64], col_s[64];

    const int t = threadIdx.x;
    const int base = blockIdx.x * 64;

    if (t < 64) {
        const int i = base + t;
        int r = 0, c = 0; float dist = 0.f, at = 0.f, emv = 0.f;
        if (i < E) {
            const float4 ra = rec[2 * i + 0];
            const float4 rb = rec[2 * i + 1];
            r = __float_as_int(ra.x); c = __float_as_int(ra.y);
            dist = ra.z; at = ra.w; emv = rb.x;
        }
        node_s[t] = r; col_s[t] = c;
        dist_s[t] = dist; attr_s[t] = at; em_s[t] = emv;
    }
    // ext-weight preload: 7 x 128 f32 (Wa1 ext rows, We1 ext rows, Wa2)
    for (int i = t; i < 896; i += 256) {
        const int r = i >> 7, c = i & 127;
        float v;
        if (r < 3)      v = Wa1[(256 + r) * D + c];
        else if (r < 6) v = We1[(128 + (r - 3)) * D + c];
        else            v = Wa2f[c];
        ew_s[r][c] = v;
    }
    __syncthreads();

    // geo = ||hh1[r] - hh1[c]|| via packed f16 diff + fdot2
    {
        const int l16 = t & 15;
        const int g = t >> 4;
#pragma unroll
        for (int it = 0; it < 4; ++it) {
            const int e = g * 4 + it;
            const uint4 vr = *(const uint4*)(hh1b + (size_t)node_s[e] * D + l16 * 8);
            const uint4 vc = *(const uint4*)(hh1b + (size_t)col_s[e] * D + l16 * 8);
            const unsigned* pr = (const unsigned*)&vr;
            const unsigned* pc = (const unsigned*)&vc;
            float s = 0.f;
#pragma unroll
            for (int q = 0; q < 4; ++q) {
                f16x2 hr2, hc2;
                __builtin_memcpy(&hr2, &pr[q], 4);
                __builtin_memcpy(&hc2, &pc[q], 4);
                const f16x2 d2 = hc2 - hr2;
                s = fdot2f(d2, d2, s);
            }
            s += __shfl_xor(s, 1); s += __shfl_xor(s, 2); s += __shfl_xor(s, 4); s += __shfl_xor(s, 8);
            if (l16 == 0) {
                const float gg = sqrtf(s + 1e-8f);
                geo_s[e] = gg;
                if (base + e < E) geo_c[base + e] = gg;
            }
        }
    }
    __syncthreads();

    // assembly: thread -> row = t>>2, col block = (t&3)*32
    // a1 = V'[r]+V[c]+ext3 (att partial) ; m1 = M'[r]+M[c]+ext3, silu -> LDS f16
    {
        const int row = t >> 2, cq = t & 3;
        const int nr = node_s[row], nc = col_s[row];
        const float dist = dist_s[row], attr = attr_s[row], geo = geo_s[row];
        const ushort* pVr = Vp + (size_t)nr * D + cq * 32;
        const ushort* pVc = Vh + (size_t)nc * D + cq * 32;
        const ushort* pMr = Mp + (size_t)nr * D + cq * 32;
        const ushort* pMc = Mh + (size_t)nc * D + cq * 32;
        float p = 0.f;
#pragma unroll
        for (int k4 = 0; k4 < 8; ++k4) {
            const int c4 = cq * 32 + k4 * 4;
            const uint2 vru = *(const uint2*)(pVr + k4 * 4);
            const uint2 vcu = *(const uint2*)(pVc + k4 * 4);
            const uint2 mru = *(const uint2*)(pMr + k4 * 4);
            const uint2 mcu = *(const uint2*)(pMc + k4 * 4);
            const float2 av01 = up2(pkadd(vru.x, vcu.x));
            const float2 av23 = up2(pkadd(vru.y, vcu.y));
            const float2 mv01 = up2(pkadd(mru.x, mcu.x));
            const float2 mv23 = up2(pkadd(mru.y, mcu.y));
            const float4 e0 = *(const float4*)&ew_s[0][c4];
            const float4 e1 = *(const float4*)&ew_s[1][c4];
            const float4 e2 = *(const float4*)&ew_s[2][c4];
            const float4 f0 = *(const float4*)&ew_s[3][c4];
            const float4 f1 = *(const float4*)&ew_s[4][c4];
            const float4 f2 = *(const float4*)&ew_s[5][c4];
            const float4 w2 = *(const float4*)&ew_s[6][c4];
            const float a0 = av01.x + dist * e0.x + attr * e1.x + geo * e2.x;
            const float a1 = av01.y + dist * e0.y + attr * e1.y + geo * e2.y;
            const float a2 = av23.x + dist * e0.z + attr * e1.z + geo * e2.z;
            const float a3 = av23.y + dist * e0.w + attr * e1.w + geo * e2.w;
            p += siluf(a0) * w2.x + siluf(a1) * w2.y + siluf(a2) * w2.z + siluf(a3) * w2.w;
            const float m0 = siluf(mv01.x + dist * f0.x + attr * f1.x + geo * f2.x);
            const float m1v = siluf(mv01.y + dist * f0.y + attr * f1.y + geo * f2.y);
            const float m2 = siluf(mv23.x + dist * f0.z + attr * f1.z + geo * f2.z);
            const float m3 = siluf(mv23.y + dist * f0.w + attr * f1.w + geo * f2.w);
            *(uint2*)&m1_s[row][c4] = make_uint2(pkh(m0, m1v), pkh(m2, m3));
        }
        p += __shfl_xor(p, 1); p += __shfl_xor(p, 2);
        if (cq == 0) att_s[row] = sigmf(p + ba2f[0]) * em_s[row];
    }
    __syncthreads();   // m1 + att ready

    // satt[r] += att (per-edge atomic; CSR-sorted -> few distinct targets)
    if (t < 64 && base + t < E) atomicAdd(&satt[node_s[t]], att_s[t]);

    // segmented reduce: s1[r][j] += att*m1 ; 4 segments x 16 rows, 2 cols/thread
    {
        const int jj = (t & 63) * 2;
        const int r0 = (t >> 6) * 16;
        float a0 = 0.f, a1 = 0.f;
        int rprev = node_s[r0];
#pragma unroll
        for (int k = 0; k < 16; ++k) {
            const int row = r0 + k;
            const int rn = node_s[row];
            if (rn != rprev) {
                atomicAdd(&s1[(size_t)rprev * D + jj + 0], a0);
                atomicAdd(&s1[(size_t)rprev * D + jj + 1], a1);
                a0 = a1 = 0.f; rprev = rn;
            }
            const float av = att_s[row];
            const float2 m = up2(*(const unsigned*)&m1_s[row][jj]);
            a0 += m.x * av; a1 += m.y * av;
        }
        atomicAdd(&s1[(size_t)rprev * D + jj + 0], a0);
        atomicAdd(&s1[(size_t)rprev * D + jj + 1], a1);
    }
}

// ---------------- node2: agg = s1@We2 + satt*be2; MLP + residual + LN + silu; P,Q ----------------
__global__ __launch_bounds__(256) void k_node2(
    const float* __restrict__ s1, const float* __restrict__ satt,
    float* hio,
    const ushort* __restrict__ pack,
    const float* __restrict__ be2f,
    const float* __restrict__ bn2f,
    const float* __restrict__ ln_g, const float* __restrict__ ln_b,
    const float* __restrict__ bc1f,
    ushort* __restrict__ Ph, ushort* __restrict__ Qh, int N) {
    __shared__ ushort ag_s[64][RS];
    __shared__ float redS[2][64], redQ[2][64];
    const int t = threadIdx.x, lane = t & 63, wave = t >> 6;
    const int quad = lane >> 4, l16 = lane & 15;
    const int mh = wave >> 1, nh = wave & 1;
    const int base = blockIdx.x * 64;

#pragma unroll
    for (int q = 0; q < 8; ++q) {
        const int f = t + 256 * q;
        const int row = f >> 5, c4 = (f & 31) << 2;
        const int node = base + row;
        float4 v = make_float4(0.f, 0.f, 0.f, 0.f);
        if (node < N) v = *(const float4*)(s1 + (size_t)node * D + c4);
        *(uint2*)&ag_s[row][c4] = make_uint2(pkh(v.x, v.y), pkh(v.z, v.w));
    }
    float bn2[4], lg[4], lb[4], bc1v[4], be2v[4];
#pragma unroll
    for (int nt = 0; nt < 4; ++nt) {
        const int col = nh * 64 + nt * 16 + l16;
        bn2[nt] = bn2f[col]; lg[nt] = ln_g[col]; lb[nt] = ln_b[col];
        bc1v[nt] = bc1f[col]; be2v[nt] = be2f[col];
    }
    __syncthreads();

    half8 aext = (half8)0;
    if (quad == 0) aext[0] = (__fp16)1.0f;

    // agg = s1@We2 + satt*be2
    f32x4 acc[2][4] = {};
    {
        const half8* pB = (const half8*)(pack + (size_t)PE2 * 4096);
#pragma unroll
        for (int ks = 0; ks < 4; ++ks) {
            half8 bfr[4];
#pragma unroll
            for (int nt = 0; nt < 4; ++nt) bfr[nt] = pB[(ks * 8 + nh * 4 + nt) * 64 + lane];
#pragma unroll
            for (int mt = 0; mt < 2; ++mt) {
                const half8 a = *(const half8*)&ag_s[mh * 32 + mt * 16 + l16][ks * 32 + quad * 8];
#pragma unroll
                for (int nt = 0; nt < 4; ++nt) acc[mt][nt] = MFMA16(a, bfr[nt], acc[mt][nt]);
            }
        }
    }
    __syncthreads();   // ag_s (s1) reads done
#pragma unroll
    for (int mt = 0; mt < 2; ++mt)
#pragma unroll
        for (int reg = 0; reg < 4; ++reg) {
            const int row = mh * 32 + mt * 16 + quad * 4 + reg;
            const int g = base + row;
            const float sa = (g < N) ? satt[g] : 0.f;
#pragma unroll
            for (int nt = 0; nt < 4; ++nt) {
                const float v = acc[mt][nt][reg] + sa * be2v[nt];
                ag_s[row][nh * 64 + nt * 16 + l16] = f2hs(v);   // agg f16 tile
            }
        }
    __syncthreads();

    // hh_mlp layer 1: silu(agg@Wn1 + bn1)
    {
        const half8* pB = (const half8*)(pack + (size_t)PN1 * 4096);
#pragma unroll
        for (int mt = 0; mt < 2; ++mt)
#pragma unroll
            for (int nt = 0; nt < 4; ++nt) acc[mt][nt] = (f32x4)0.0f;
#pragma unroll
        for (int ks = 0; ks < 5; ++ks) {
            half8 bfr[4];
#pragma unroll
            for (int nt = 0; nt < 4; ++nt) bfr[nt] = pB[(ks * 8 + nh * 4 + nt) * 64 + lane];
#pragma unroll
            for (int mt = 0; mt < 2; ++mt) {
                const half8 a = (ks < 4) ? *(const half8*)&ag_s[mh * 32 + mt * 16 + l16][ks * 32 + quad * 8]
                                         : aext;
#pragma unroll
                for (int nt = 0; nt < 4; ++nt) acc[mt][nt] = MFMA16(a, bfr[nt], acc[mt][nt]);
            }
        }
    }
    __syncthreads();
#pragma unroll
    for (int mt = 0; mt < 2; ++mt)
#pragma unroll
        for (int reg = 0; reg < 4; ++reg) {
            const int row = mh * 32 + mt * 16 + quad * 4 + reg;
#pragma unroll
            for (int nt = 0; nt < 4; ++nt)
                ag_s[row][nh * 64 + nt * 16 + l16] = f2hs(siluf(acc[mt][nt][reg]));
        }
    __syncthreads();

    {
        const half8* pB = (const half8*)(pack + (size_t)PN2 * 4096);
#pragma unroll
        for (int mt = 0; mt < 2; ++mt)
#pragma unroll
            for (int nt = 0; nt < 4; ++nt) acc[mt][nt] = (f32x4)0.0f;
#pragma unroll
        for (int ks = 0; ks < 4; ++ks) {
            half8 bfr[4];
#pragma unroll
            for (int nt = 0; nt < 4; ++nt) bfr[nt] = pB[(ks * 8 + nh * 4 + nt) * 64 + lane];
#pragma unroll
            for (int mt = 0; mt < 2; ++mt) {
                const half8 a = *(const half8*)&ag_s[mh * 32 + mt * 16 + l16][ks * 32 + quad * 8];
#pragma unroll
                for (int nt = 0; nt < 4; ++nt) acc[mt][nt] = MFMA16(a, bfr[nt], acc[mt][nt]);
            }
        }
    }
#pragma unroll
    for (int mt = 0; mt < 2; ++mt)
#pragma unroll
        for (int reg = 0; reg < 4; ++reg) {
            const int row = mh * 32 + mt * 16 + quad * 4 + reg;
            const int g = base + row;
            float s = 0.f, qq = 0.f;
#pragma unroll
            for (int nt = 0; nt < 4; ++nt) {
                const int col = nh * 64 + nt * 16 + l16;
                float v = acc[mt][nt][reg] + bn2[nt];
                if (g < N) v += hio[(size_t)g * D + col];
                acc[mt][nt][reg] = v;
                s += v; qq += v * v;
            }
            s += __shfl_xor(s, 1); s += __shfl_xor(s, 2); s += __shfl_xor(s, 4); s += __shfl_xor(s, 8);
            qq += __shfl_xor(qq, 1); qq += __shfl_xor(qq, 2); qq += __shfl_xor(qq, 4); qq += __shfl_xor(qq, 8);
            if (l16 == 0) { redS[nh][row] = s; redQ[nh][row] = qq; }
        }
    __syncthreads();

#pragma unroll
    for (int mt = 0; mt < 2; ++mt)
#pragma unroll
        for (int reg = 0; reg < 4; ++reg) {
            const int row = mh * 32 + mt * 16 + quad * 4 + reg;
            const int g = base + row;
            const float mu = (redS[0][row] + redS[1][row]) * (1.0f / D);
            const float var = (redQ[0][row] + redQ[1][row]) * (1.0f / D) - mu * mu;
            const float rstd = rsqrtf(var + 1e-5f);
#pragma unroll
            for (int nt = 0; nt < 4; ++nt) {
                const int col = nh * 64 + nt * 16 + l16;
                const float hn = (acc[mt][nt][reg] - mu) * rstd * lg[nt] + lb[nt];
                const float o = siluf(hn);
                ag_s[row][col] = f2hs(o);                     // hh2 f16 for P/Q K-loops
                if (g < N) hio[(size_t)g * D + col] = o;
            }
        }
    __syncthreads();

    // P = hh2@Wc1_top + bc1 (f16)
    {
        f32x4 a2[2][4] = {};
        const half8* pB = (const half8*)(pack + (size_t)PP * 4096);
#pragma unroll
        for (int ks = 0; ks < 4; ++ks) {
            half8 bfr[4];
#pragma unroll
            for (int nt = 0; nt < 4; ++nt) bfr[nt] = pB[(ks * 8 + nh * 4 + nt) * 64 + lane];
#pragma unroll
            for (int mt = 0; mt < 2; ++mt) {
                const half8 a = *(const half8*)&ag_s[mh * 32 + mt * 16 + l16][ks * 32 + quad * 8];
#pragma unroll
                for (int nt = 0; nt < 4; ++nt) a2[mt][nt] = MFMA16(a, bfr[nt], a2[mt][nt]);
            }
        }
#pragma unroll
        for (int mt = 0; mt < 2; ++mt)
#pragma unroll
            for (int reg = 0; reg < 4; ++reg) {
                const int g = base + mh * 32 + mt * 16 + quad * 4 + reg;
                if (g < N)
#pragma unroll
                    for (int nt = 0; nt < 4; ++nt)
                        Ph[(size_t)g * D + nh * 64 + nt * 16 + l16] = f2hs(a2[mt][nt][reg] + bc1v[nt]);
            }
    }
    // Q = hh2@Wc1_bot (f16)
    {
        f32x4 a2[2][4] = {};
        const half8* pB = (const half8*)(pack + (size_t)PQ * 4096);
#pragma unroll
        for (int ks = 0; ks < 4; ++ks) {
            half8 bfr[4];
#pragma unroll
            for (int nt = 0; nt < 4; ++nt) bfr[nt] = pB[(ks * 8 + nh * 4 + nt) * 64 + lane];
#pragma unroll
            for (int mt = 0; mt < 2; ++mt) {
                const half8 a = *(const half8*)&ag_s[mh * 32 + mt * 16 + l16][ks * 32 + quad * 8];
#pragma unroll
                for (int nt = 0; nt < 4; ++nt) a2[mt][nt] = MFMA16(a, bfr[nt], a2[mt][nt]);
            }
        }
#pragma unroll
        for (int mt = 0; mt < 2; ++mt)
#pragma unroll
            for (int reg = 0; reg < 4; ++reg) {
                const int g = base + mh * 32 + mt * 16 + quad * 4 + reg;
                if (g < N)
#pragma unroll
                    for (int nt = 0; nt < 4; ++nt)
                        Qh[(size_t)g * D + nh * 64 + nt * 16 + l16] = f2hs(a2[mt][nt][reg]);
            }
    }
}

// ---------------- edge phase 2: assemble c1, GEMM2, coord reduce ----------------
__global__ __launch_bounds__(256, 6) void k_edge2(
    const float4* __restrict__ rec, const float* __restrict__ geo_c,
    const ushort* __restrict__ Ph, const ushort* __restrict__ Qh,
    const ushort* __restrict__ pack,
    const float* __restrict__ Wc1,
    const float* __restrict__ bc2f, const float* __restrict__ Wc3f,
    float* __restrict__ aggx, int E) {
    __shared__ ushort c1_s[64][RS];
    __shared__ float ew_s[3][128];
    __shared__ float dist_s[64], attr_s[64], geo_s[64], tr_s[64];
    __shared__ float cdx_s[64], cdy_s[64], cdz_s[64];
    __shared__ int node_s[64], col_s[64];
    __shared__ float mp_s[4][64];

    const int t = threadIdx.x, lane = t & 63, w = t >> 6;
    const int quad = lane >> 4, l16 = lane & 15;
    const int base = blockIdx.x * 64;

    if (t < 64) {
        const int i = base + t;
        int r = 0, c = 0;
        float dist = 1.f, geo = 0.f, at = 0.f, emv = 0.f, cdx = 0.f, cdy = 0.f, cdz = 0.f;
        if (i < E) {
            const float4 ra = rec[2 * i + 0];
            const float4 rb = rec[2 * i + 1];
            r = __float_as_int(ra.x); c = __float_as_int(ra.y);
            dist = ra.z; at = ra.w;
            emv = rb.x; cdx = rb.y; cdy = rb.z; cdz = rb.w;
            geo = geo_c[i];
        }
        node_s[t] = r; col_s[t] = c;
        dist_s[t] = dist; geo_s[t] = geo; attr_s[t] = at; tr_s[t] = emv;  // tr_s holds em
        cdx_s[t] = cdx; cdy_s[t] = cdy; cdz_s[t] = cdz;
    }
    for (int i = t; i < 384; i += 256) {
        const int r = i >> 7, c = i & 127;
        ew_s[r][c] = Wc1[(256 + r) * D + c];
    }
    float bc2[2], wc3[2];
#pragma unroll
    for (int nt = 0; nt < 2; ++nt) {
        const int col = w * 32 + nt * 16 + l16;
        bc2[nt] = bc2f[col]; wc3[nt] = Wc3f[col];
    }
    __syncthreads();

    // c1 assembly: c1 = silu(P[r] + Q[c] + ext3), ext rows from LDS
    {
        const int row = t >> 2, cq = t & 3;
        const int nr = node_s[row], nc = col_s[row];
        const float dist = dist_s[row], attr = attr_s[row], geo = geo_s[row];
        const ushort* pP = Ph + (size_t)nr * D + cq * 32;
        const ushort* pQ = Qh + (size_t)nc * D + cq * 32;
#pragma unroll
        for (int k4 = 0; k4 < 8; ++k4) {
            const int c4 = cq * 32 + k4 * 4;
            const uint2 pu = *(const uint2*)(pP + k4 * 4);
            const uint2 qu = *(const uint2*)(pQ + k4 * 4);
            const float2 s01 = up2(pkadd(pu.x, qu.x));
            const float2 s23 = up2(pkadd(pu.y, qu.y));
            const float4 e0 = *(const float4*)&ew_s[0][c4];
            const float4 e1 = *(const float4*)&ew_s[1][c4];
            const float4 e2 = *(const float4*)&ew_s[2][c4];
            const float c0 = siluf(s01.x + dist * e0.x + attr * e1.x + geo * e2.x);
            const float c1 = siluf(s01.y + dist * e0.y + attr * e1.y + geo * e2.y);
            const float c2 = siluf(s23.x + dist * e0.z + attr * e1.z + geo * e2.z);
            const float c3 = siluf(s23.y + dist * e0.w + attr * e1.w + geo * e2.w);
            *(uint2*)&c1_s[row][c4] = make_uint2(pkh(c0, c1), pkh(c2, c3));
        }
    }
    __syncthreads();

    // GEMM2: c2 = silu(c1@Wc2 + bc2); m-partials over this wave's cols
    {
        f32x4 acc[4][2] = {};
        const half8* pB = (const half8*)(pack + (size_t)PC2 * 4096);
#pragma unroll
        for (int ks = 0; ks < 4; ++ks) {
            const half8 b0 = pB[(ks * 8 + w * 2 + 0) * 64 + lane];
            const half8 b1 = pB[(ks * 8 + w * 2 + 1) * 64 + lane];
#pragma unroll
            for (int mt = 0; mt < 4; ++mt) {
                const half8 a = *(const half8*)&c1_s[mt * 16 + l16][ks * 32 + quad * 8];
                acc[mt][0] = MFMA16(a, b0, acc[mt][0]);
                acc[mt][1] = MFMA16(a, b1, acc[mt][1]);
            }
        }
#pragma unroll
        for (int mt = 0; mt < 4; ++mt)
#pragma unroll
            for (int reg = 0; reg < 4; ++reg) {
                float p = siluf(acc[mt][0][reg] + bc2[0]) * wc3[0]
                        + siluf(acc[mt][1][reg] + bc2[1]) * wc3[1];
                p += __shfl_xor(p, 1); p += __shfl_xor(p, 2); p += __shfl_xor(p, 4); p += __shfl_xor(p, 8);
                if (l16 == 0) mp_s[w][mt * 16 + quad * 4 + reg] = p;
            }
    }
    __syncthreads();

    if (t < 64) {
        const float m = mp_s[0][t] + mp_s[1][t] + mp_s[2][t] + mp_s[3][t];
        tr_s[t] = m * tr_s[t];   // m * em
        if (base + t >= E) tr_s[t] = 0.f;
    }
    __syncthreads();

    // segmented per-block reduce of trans into aggx (3 lanes x,y,z; two 32-row halves)
    {
        const int h = t >> 7, tt = t & 127;
        if (tt < 3) {
            const float* cds = (tt == 0) ? cdx_s : (tt == 1) ? cdy_s : cdz_s;
            float acc = 0.f;
            int rprev = node_s[h * 32];
#pragma unroll
            for (int k = 0; k < 32; ++k) {
                const int row = h * 32 + k;
                const int rn = node_s[row];
                if (rn != rprev) {
                    atomicAdd(&aggx[rprev * 4 + tt], acc);
                    acc = 0.f; rprev = rn;
                }
                acc += cds[row] * tr_s[row];
            }
            atomicAdd(&aggx[rprev * 4 + tt], acc);
        }
    }
}

// ---------------- coord epilogue ----------------
__global__ void k_coord(const float* __restrict__ x, const float* __restrict__ nmask,
                        const float* __restrict__ aggx, float* __restrict__ out_x, int N) {
    const int idx = blockIdx.x * blockDim.x + threadIdx.x;
    if (idx >= N * 3) return;
    const int i = idx / 3, d = idx - i * 3;
    out_x[idx] = (x[idx] + aggx[i * 4 + d] * (1.0f / 100.0f)) * nmask[i];
}

extern "C" void kernel_launch(void* const* d_in, const int* in_sizes, int n_in,
                              void* d_out, int out_size, void* d_ws, size_t ws_size,
                              hipStream_t stream) {
    const float* h     = (const float*)d_in[0];
    const float* x     = (const float*)d_in[1];
    const int*   eidx  = (const int*)d_in[2];
    const float* nmask = (const float*)d_in[3];
    const float* emask = (const float*)d_in[4];
    const float* eattr = (const float*)d_in[5];
    const float* W_lin = (const float*)d_in[6];
    const float* b_lin = (const float*)d_in[7];
    const float* We1   = (const float*)d_in[8];
    const float* be1   = (const float*)d_in[9];
    const float* We2   = (const float*)d_in[10];
    const float* be2   = (const float*)d_in[11];
    const float* Wn1   = (const float*)d_in[12];
    const float* bn1   = (const float*)d_in[13];
    const float* Wn2   = (const float*)d_in[14];
    const float* bn2   = (const float*)d_in[15];
    const float* Wa1   = (const float*)d_in[16];
    const float* ba1   = (const float*)d_in[17];
    const float* Wa2   = (const float*)d_in[18];
    const float* ba2   = (const float*)d_in[19];
    const float* ln_g  = (const float*)d_in[20];
    const float* ln_b  = (const float*)d_in[21];
    const float* Wc1   = (const float*)d_in[22];
    const float* bc1   = (const float*)d_in[23];
    const float* Wc2   = (const float*)d_in[24];
    const float* bc2   = (const float*)d_in[25];
    const float* Wc3   = (const float*)d_in[26];

    const int N = in_sizes[0] / D;
    const int E = in_sizes[2] / 2;

    // ws layout (256-B aligned regions), ~60 MB
    char* wp = (char*)d_ws;
    auto take = [&](size_t bytes) -> void* {
        void* p = wp; wp += (bytes + 255) & ~(size_t)255; return p;
    };
    float*  s1    = (float*)take((size_t)N * D * 4);   // ┐ zeroed as one
    float*  aggx  = (float*)take((size_t)N * 4 * 4);   // │ contiguous
    float*  satt  = (float*)take((size_t)N * 4);       // │ region
    int*    cnt   = (int*)take((size_t)N * 4);         // ┘
    int*    cur   = (int*)take((size_t)N * 4);
    float4* rec   = (float4*)take((size_t)E * 32);
    float*  geo_c = (float*)take((size_t)E * 4);
    ushort* hh1b  = (ushort*)take((size_t)N * D * 2);
    ushort* Vp    = (ushort*)take((size_t)N * D * 2);
    ushort* Vh    = (ushort*)take((size_t)N * D * 2);
    ushort* Mp    = (ushort*)take((size_t)N * D * 2);
    ushort* Mh    = (ushort*)take((size_t)N * D * 2);
    ushort* Ph    = (ushort*)take((size_t)N * D * 2);
    ushort* Qh    = (ushort*)take((size_t)N * D * 2);
    ushort* pack  = (ushort*)take((size_t)NPACK * 4096 * 2);

    float* out_h = (float*)d_out;          // doubles as hh fp32 storage
    float* out_x = out_h + (size_t)N * D;

    const int EB = (E + 63) / 64;
    const int NB = (N + 63) / 64;
    const long zn = ((char*)(cnt + N) - (char*)s1) / 4;   // s1..cnt contiguous

    k_zero<<<2048, 256, 0, stream>>>(s1, zn);
    k_packall<<<NPACK, 256, 0, stream>>>(W_lin, b_lin, Wa1, We1, We2,
                                         Wn1, bn1, Wn2, Wc1, Wc2, pack);
    k_hist<<<1024, 256, 0, stream>>>(eidx, cnt, E);
    k_scan<<<1, 1024, 0, stream>>>(cnt, cur, N);
    k_scatter_build<<<1024, 256, 0, stream>>>(eidx, x, eattr, emask, cur, rec, E);
    k_node_lin<<<NB, 256, 0, stream>>>(h, pack, out_h, hh1b, Vp, Vh, Mp, Mh, ba1, be1, N);
    k_edge1<<<EB, 256, 0, stream>>>(rec, hh1b, Vp, Vh, Mp, Mh, Wa1, We1,
                                    Wa2, ba2, s1, satt, geo_c, E);
    k_node2<<<NB, 256, 0, stream>>>(s1, satt, out_h, pack, be2, bn2, ln_g, ln_b,
                                    bc1, Ph, Qh, N);
    k_edge2<<<EB, 256, 0, stream>>>(rec, geo_c, Ph, Qh, pack, Wc1, bc2, Wc3, aggx, E);
    k_coord<<<(N * 3 + 255) / 256, 256, 0, stream>>>(x, nmask, aggx, out_x, N);
}

// Round 10
// 491.631 us; speedup vs baseline: 1.3747x; 1.1066x over previous
//
#include <hip/hip_runtime.h>
#include <hip/hip_bf16.h>

// EquivariantBlock — Round 19.
// R18 post-mortem: the We2 fold (edge1 without GEMM3) measured WORSE (edge1
// 140->215us): GEMM3's MFMA phase was hiding the random c-side gather latency
// via inter-block overlap; without it edge1 is latency-bound (VALU 64->36%,
// stall +88us). REVERT to R15 (verified 461us total, edge1 140us).
// R19 on top: interleave the per-node streams — G1r[n]={V'[n],M'[n]},
// G1c[n]={V[n],M[n]} in 16B chunks (4 f16 V + 4 f16 M per column-quad), so the
// assembly loop does 2 uint4 loads per k4 instead of 4 uint2 (halves gather
// load count + address VALU; one contiguous 512B region per c-node).

#define D 128
#define RS 136          // LDS row stride in fp16 units (128 + 8 pad; 272B rows)

typedef unsigned short ushort;
typedef __fp16 half8 __attribute__((ext_vector_type(8)));     // MFMA operand (V8h)
typedef __fp16 h16x2 __attribute__((ext_vector_type(2)));     // builtin boundary
typedef _Float16 f16x2 __attribute__((ext_vector_type(2)));   // packed math
typedef __attribute__((ext_vector_type(4))) float f32x4;

__device__ __forceinline__ float rcpf(float x) { return __builtin_amdgcn_rcpf(x); }
__device__ __forceinline__ float siluf(float x) { return x * rcpf(1.0f + __expf(-x)); }
__device__ __forceinline__ float sigmf(float x) { return rcpf(1.0f + __expf(-x)); }
__device__ __forceinline__ ushort f2hs(float f) {
    _Float16 h = (_Float16)f; ushort u; __builtin_memcpy(&u, &h, 2); return u;
}
__device__ __forceinline__ unsigned pkh(float lo, float hi) {
    auto h = __builtin_amdgcn_cvt_pkrtz(lo, hi);   // v_cvt_pkrtz_f16_f32
    unsigned u; __builtin_memcpy(&u, &h, 4); return u;
}
__device__ __forceinline__ unsigned pkadd(unsigned a, unsigned b) {  // packed f16 a+b
    f16x2 x, y; __builtin_memcpy(&x, &a, 4); __builtin_memcpy(&y, &b, 4);
    f16x2 d = x + y; unsigned r; __builtin_memcpy(&r, &d, 4); return r;
}
__device__ __forceinline__ float2 up2(unsigned u) {  // 2 f16 -> 2 f32
    f16x2 h; __builtin_memcpy(&h, &u, 4);
    return make_float2((float)h.x, (float)h.y);
}
__device__ __forceinline__ float fdot2f(f16x2 a, f16x2 b, float c) {
#if __has_builtin(__builtin_amdgcn_fdot2)
    h16x2 ah, bh;
    __builtin_memcpy(&ah, &a, 4); __builtin_memcpy(&bh, &b, 4);
    return __builtin_amdgcn_fdot2(ah, bh, c, false);
#else
    return c + (float)a.x * (float)b.x + (float)a.y * (float)b.y;
#endif
}
#define MFMA16(a, b, c) __builtin_amdgcn_mfma_f32_16x16x32_f16((a), (b), (c), 0, 0, 0)

// packed-weight block offsets (units of 4096 ushorts)
#define PWLIN 0     // W_lin + ext(b_lin)            [5]
#define PU    5     // Wa1[0:128]  (V' = hh@W1+ba1)  [4]
#define PV    9     // Wa1[128:256]                  [4]
#define PM    13    // We1[0:128]                    [4]
#define PE2   17    // We2                           [4]
#define PN1   21    // Wn1 + ext(bn1)                [5]
#define PN2   26    // Wn2                           [4]
#define PP    30    // Wc1[0:128]                    [4]
#define PQ    34    // Wc1[128:256]                  [4]
#define PC2   38    // Wc2                           [4]
#define NPACK 42

// interleaved chunk index: col -> (col/4)*8 + (col&3); M side at +4
__device__ __forceinline__ int g1idx(int col) { return ((col >> 2) << 3) + (col & 3); }

// ---------------- zero scratch ----------------
__global__ void k_zero(float* __restrict__ p, long n) {
    long i = (long)blockIdx.x * blockDim.x + threadIdx.x;
    long stride = (long)gridDim.x * blockDim.x;
    for (; i < n; i += stride) p[i] = 0.0f;
}

// ---------------- CSR build ----------------
__global__ void k_hist(const int* __restrict__ eidx, int* __restrict__ cnt, int E) {
    int i = blockIdx.x * blockDim.x + threadIdx.x;
    const int stride = gridDim.x * blockDim.x;
    for (; i < E; i += stride) atomicAdd(&cnt[eidx[i]], 1);
}

__global__ __launch_bounds__(1024) void k_scan(const int* __restrict__ cnt,
                                               int* __restrict__ cur, int N) {
    __shared__ int part[1024];
    const int t = threadIdx.x;
    const int chunk = (N + 1023) / 1024;
    int s = 0;
    for (int k = 0; k < chunk; ++k) {
        const int i = t * chunk + k;
        if (i < N) s += cnt[i];
    }
    part[t] = s;
    __syncthreads();
    for (int d = 1; d < 1024; d <<= 1) {
        const int v = (t >= d) ? part[t - d] : 0;
        __syncthreads();
        part[t] += v;
        __syncthreads();
    }
    int base = (t == 0) ? 0 : part[t - 1];
    for (int k = 0; k < chunk; ++k) {
        const int i = t * chunk + k;
        if (i < N) { cur[i] = base; base += cnt[i]; }
    }
}

// scatter + build CSR-ordered 32B AoS records: {r,c,dist,attr | em,cdx,cdy,cdz}
__global__ void k_scatter_build(
    const int* __restrict__ eidx, const float* __restrict__ x,
    const float* __restrict__ eattr, const float* __restrict__ emask,
    int* __restrict__ cur, float4* __restrict__ rec, int E) {
    int i = blockIdx.x * blockDim.x + threadIdx.x;
    const int stride = gridDim.x * blockDim.x;
    for (; i < E; i += stride) {
        const int r = eidx[i], c = eidx[E + i];
        const int p = atomicAdd(&cur[r], 1);
        const float dx = x[r * 3 + 0] - x[c * 3 + 0];
        const float dy = x[r * 3 + 1] - x[c * 3 + 1];
        const float dz = x[r * 3 + 2] - x[c * 3 + 2];
        const float dist = sqrtf(dx * dx + dy * dy + dz * dz + 1e-8f);
        const float inv = rcpf(dist + 1.0f);
        rec[2 * p + 0] = make_float4(__int_as_float(r), __int_as_float(c), dist, eattr[i]);
        rec[2 * p + 1] = make_float4(emask[i], dx * inv, dy * inv, dz * inv);
    }
}

// ---------------- fused weight pack (fp16) ----------------
__global__ __launch_bounds__(256) void k_packall(
    const float* __restrict__ W_lin, const float* __restrict__ b_lin,
    const float* __restrict__ Wa1,
    const float* __restrict__ We1,
    const float* __restrict__ We2,
    const float* __restrict__ Wn1, const float* __restrict__ bn1,
    const float* __restrict__ Wn2,
    const float* __restrict__ Wc1,
    const float* __restrict__ Wc2,
    ushort* __restrict__ pack) {
    const int b = blockIdx.x, t = threadIdx.x;
    const float* W = nullptr; const float* bias = nullptr;
    int kbase = 0, fold = 0, ext = 0, nW = 0;
    if (b < 5)       { W = W_lin; bias = b_lin; if (b == 4) { ext = 1; nW = 0; } else kbase = b * 32; }
    else if (b < 9)  { W = Wa1; kbase = (b - 5) * 32; }                    // PU (top half)
    else if (b < 13) { W = Wa1; kbase = 128 + (b - 9) * 32; }              // PV
    else if (b < 17) { W = We1; kbase = (b - 13) * 32; }                   // PM
    else if (b < 21) { W = We2; kbase = (b - 17) * 32; }                   // PE2
    else if (b < 26) { int k = b - 21; W = Wn1; bias = bn1; if (k == 4) { ext = 1; nW = 0; } else kbase = k * 32; }
    else if (b < 30) { W = Wn2; kbase = (b - 26) * 32; }                   // PN2
    else if (b < 34) { W = Wc1; kbase = (b - 30) * 32; }                   // PP
    else if (b < 38) { W = Wc1; kbase = 128 + (b - 34) * 32; }             // PQ
    else             { W = Wc2; kbase = (b - 38) * 32; }                   // PC2
    ushort* dst = pack + (size_t)b * 4096;
#pragma unroll
    for (int i = 0; i < 16; ++i) {
        const int e = t + 256 * i;
        const int j = e & 7, lane = (e >> 3) & 63, nt = e >> 9;
        const int kl = (lane >> 4) * 8 + j;
        const int n = nt * 16 + (lane & 15);
        float v;
        if (!ext) {
            v = W[(kbase + kl) * D + n];
            if (fold) v += W[(kbase + kl + 128) * D + n];
        } else {
            v = (kl < nW) ? W[(kbase + kl) * D + n] : (kl == nW ? bias[n] : 0.0f);
        }
        dst[e] = f2hs(v);
    }
}

// ---------------- node_lin: hh = h @ W_lin + b; G1r={V',M'}, G1c={V,M} precompute ----------------
__global__ __launch_bounds__(256) void k_node_lin(
    const float* __restrict__ h, const ushort* __restrict__ pack,
    float* __restrict__ hh, ushort* __restrict__ hh1b,
    ushort* __restrict__ G1r, ushort* __restrict__ G1c,
    const float* __restrict__ ba1f, const float* __restrict__ be1f, int N) {
    __shared__ ushort hs[64][RS];
    const int t = threadIdx.x, lane = t & 63, wave = t >> 6;
    const int quad = lane >> 4, l16 = lane & 15;
    const int mh = wave >> 1, nh = wave & 1;
    const int base = blockIdx.x * 64;

#pragma unroll
    for (int q = 0; q < 8; ++q) {
        const int f = t + 256 * q;
        const int row = f >> 5, c4 = (f & 31) << 2;
        const int node = base + row;
        float4 v = make_float4(0.f, 0.f, 0.f, 0.f);
        if (node < N) v = *(const float4*)(h + (size_t)node * D + c4);
        *(uint2*)&hs[row][c4] = make_uint2(pkh(v.x, v.y), pkh(v.z, v.w));
    }
    float ba1v[4], be1v[4];
#pragma unroll
    for (int nt = 0; nt < 4; ++nt) {
        const int col = nh * 64 + nt * 16 + l16;
        ba1v[nt] = ba1f[col]; be1v[nt] = be1f[col];
    }
    __syncthreads();

    half8 aext = (half8)0;
    if (quad == 0) aext[0] = (__fp16)1.0f;

    f32x4 acc[2][4] = {};
    {
        const half8* pB = (const half8*)(pack + (size_t)PWLIN * 4096);
#pragma unroll
        for (int ks = 0; ks < 5; ++ks) {
            half8 bfr[4];
#pragma unroll
            for (int nt = 0; nt < 4; ++nt) bfr[nt] = pB[(ks * 8 + nh * 4 + nt) * 64 + lane];
#pragma unroll
            for (int mt = 0; mt < 2; ++mt) {
                const half8 a = (ks < 4) ? *(const half8*)&hs[mh * 32 + mt * 16 + l16][ks * 32 + quad * 8]
                                         : aext;
#pragma unroll
                for (int nt = 0; nt < 4; ++nt) acc[mt][nt] = MFMA16(a, bfr[nt], acc[mt][nt]);
            }
        }
    }
    __syncthreads();   // all hs reads done before overwrite
    // store hh (f32 out + f16) and overwrite hs with hh f16 for the precompute K-loops
#pragma unroll
    for (int mt = 0; mt < 2; ++mt)
#pragma unroll
        for (int reg = 0; reg < 4; ++reg) {
            const int row = mh * 32 + mt * 16 + quad * 4 + reg;
            const int g = base + row;
#pragma unroll
            for (int nt = 0; nt < 4; ++nt) {
                const int col = nh * 64 + nt * 16 + l16;
                const float v = acc[mt][nt][reg];
                const ushort hv = f2hs(v);
                hs[row][col] = hv;
                if (g < N) {
                    hh[(size_t)g * D + col] = v;
                    hh1b[(size_t)g * D + col] = hv;
                }
            }
        }
    __syncthreads();

    // V' = hh@Wa1_top + ba1 -> G1r[idx]
    {
        f32x4 a2[2][4] = {};
        const half8* pB = (const half8*)(pack + (size_t)PU * 4096);
#pragma unroll
        for (int ks = 0; ks < 4; ++ks) {
            half8 bfr[4];
#pragma unroll
            for (int nt = 0; nt < 4; ++nt) bfr[nt] = pB[(ks * 8 + nh * 4 + nt) * 64 + lane];
#pragma unroll
            for (int mt = 0; mt < 2; ++mt) {
                const half8 a = *(const half8*)&hs[mh * 32 + mt * 16 + l16][ks * 32 + quad * 8];
#pragma unroll
                for (int nt = 0; nt < 4; ++nt) a2[mt][nt] = MFMA16(a, bfr[nt], a2[mt][nt]);
            }
        }
#pragma unroll
        for (int mt = 0; mt < 2; ++mt)
#pragma unroll
            for (int reg = 0; reg < 4; ++reg) {
                const int g = base + mh * 32 + mt * 16 + quad * 4 + reg;
                if (g < N)
#pragma unroll
                    for (int nt = 0; nt < 4; ++nt) {
                        const int col = nh * 64 + nt * 16 + l16;
                        G1r[(size_t)g * 256 + g1idx(col)] = f2hs(a2[mt][nt][reg] + ba1v[nt]);
                    }
            }
    }
    // V = hh@Wa1_bot -> G1c[idx]
    {
        f32x4 a2[2][4] = {};
        const half8* pB = (const half8*)(pack + (size_t)PV * 4096);
#pragma unroll
        for (int ks = 0; ks < 4; ++ks) {
            half8 bfr[4];
#pragma unroll
            for (int nt = 0; nt < 4; ++nt) bfr[nt] = pB[(ks * 8 + nh * 4 + nt) * 64 + lane];
#pragma unroll
            for (int mt = 0; mt < 2; ++mt) {
                const half8 a = *(const half8*)&hs[mh * 32 + mt * 16 + l16][ks * 32 + quad * 8];
#pragma unroll
                for (int nt = 0; nt < 4; ++nt) a2[mt][nt] = MFMA16(a, bfr[nt], a2[mt][nt]);
            }
        }
#pragma unroll
        for (int mt = 0; mt < 2; ++mt)
#pragma unroll
            for (int reg = 0; reg < 4; ++reg) {
                const int g = base + mh * 32 + mt * 16 + quad * 4 + reg;
                if (g < N)
#pragma unroll
                    for (int nt = 0; nt < 4; ++nt) {
                        const int col = nh * 64 + nt * 16 + l16;
                        G1c[(size_t)g * 256 + g1idx(col)] = f2hs(a2[mt][nt][reg]);
                    }
            }
    }
    // M = hh@We1_top -> G1c[idx+4] ; M' = be1 - M -> G1r[idx+4]
    {
        f32x4 a2[2][4] = {};
        const half8* pB = (const half8*)(pack + (size_t)PM * 4096);
#pragma unroll
        for (int ks = 0; ks < 4; ++ks) {
            half8 bfr[4];
#pragma unroll
            for (int nt = 0; nt < 4; ++nt) bfr[nt] = pB[(ks * 8 + nh * 4 + nt) * 64 + lane];
#pragma unroll
            for (int mt = 0; mt < 2; ++mt) {
                const half8 a = *(const half8*)&hs[mh * 32 + mt * 16 + l16][ks * 32 + quad * 8];
#pragma unroll
                for (int nt = 0; nt < 4; ++nt) a2[mt][nt] = MFMA16(a, bfr[nt], a2[mt][nt]);
            }
        }
#pragma unroll
        for (int mt = 0; mt < 2; ++mt)
#pragma unroll
            for (int reg = 0; reg < 4; ++reg) {
                const int g = base + mh * 32 + mt * 16 + quad * 4 + reg;
                if (g < N)
#pragma unroll
                    for (int nt = 0; nt < 4; ++nt) {
                        const int col = nh * 64 + nt * 16 + l16;
                        const float v = a2[mt][nt][reg];
                        const int idx = g1idx(col) + 4;
                        G1c[(size_t)g * 256 + idx] = f2hs(v);
                        G1r[(size_t)g * 256 + idx] = f2hs(be1v[nt] - v);
                    }
            }
    }
}

// ---------------- edge phase 1: gather-assemble a1/m1, GEMM3, segmented reduce ----------------
__global__ __launch_bounds__(256, 6) void k_edge1(
    const float4* __restrict__ rec,
    const ushort* __restrict__ hh1b,
    const ushort* __restrict__ G1r, const ushort* __restrict__ G1c,
    const ushort* __restrict__ pack,
    const float* __restrict__ Wa1, const float* __restrict__ We1,
    const float* __restrict__ Wa2f, const float* __restrict__ ba2f,
    const float* __restrict__ be2f,
    float* __restrict__ agg, float* __restrict__ geo_c, int E) {
    __shared__ ushort m1_s[64][RS];      // 17408B: m1 f16 tile; msg f32 overlay [32][RS]
    __shared__ float ew_s[7][128];       // rows: Wa1e0..2, We1e0..2, Wa2
    __shared__ float dist_s[64], attr_s[64], geo_s[64], att_s[64], em_s[64];
    __shared__ int node_s[64], col_s[64];

    float (*msg_s)[RS] = (float(*)[RS])&m1_s[0][0];   // 32*136*4 = 17408 exact

    const int t = threadIdx.x, lane = t & 63, w = t >> 6;
    const int quad = lane >> 4, l16 = lane & 15;
    const int base = blockIdx.x * 64;

    if (t < 64) {
        const int i = base + t;
        int r = 0, c = 0; float dist = 0.f, at = 0.f, emv = 0.f;
        if (i < E) {
            const float4 ra = rec[2 * i + 0];
            const float4 rb = rec[2 * i + 1];
            r = __float_as_int(ra.x); c = __float_as_int(ra.y);
            dist = ra.z; at = ra.w; emv = rb.x;
        }
        node_s[t] = r; col_s[t] = c;
        dist_s[t] = dist; attr_s[t] = at; em_s[t] = emv;
    }
    // ext-weight preload: 7 x 128 f32 (Wa1 ext rows, We1 ext rows, Wa2)
    for (int i = t; i < 896; i += 256) {
        const int r = i >> 7, c = i & 127;
        float v;
        if (r < 3)      v = Wa1[(256 + r) * D + c];
        else if (r < 6) v = We1[(128 + (r - 3)) * D + c];
        else            v = Wa2f[c];
        ew_s[r][c] = v;
    }
    float b3[2];
#pragma unroll
    for (int nt = 0; nt < 2; ++nt) b3[nt] = be2f[w * 32 + nt * 16 + l16];
    __syncthreads();

    // geo = ||hh1[r] - hh1[c]|| via packed f16 diff + fdot2
    {
        const int g = t >> 4;
#pragma unroll
        for (int it = 0; it < 4; ++it) {
            const int e = g * 4 + it;
            const uint4 vr = *(const uint4*)(hh1b + (size_t)node_s[e] * D + l16 * 8);
            const uint4 vc = *(const uint4*)(hh1b + (size_t)col_s[e] * D + l16 * 8);
            const unsigned* pr = (const unsigned*)&vr;
            const unsigned* pc = (const unsigned*)&vc;
            float s = 0.f;
#pragma unroll
            for (int q = 0; q < 4; ++q) {
                f16x2 hr2, hc2;
                __builtin_memcpy(&hr2, &pr[q], 4);
                __builtin_memcpy(&hc2, &pc[q], 4);
                const f16x2 d2 = hc2 - hr2;
                s = fdot2f(d2, d2, s);
            }
            s += __shfl_xor(s, 1); s += __shfl_xor(s, 2); s += __shfl_xor(s, 4); s += __shfl_xor(s, 8);
            if (l16 == 0) {
                const float gg = sqrtf(s + 1e-8f);
                geo_s[e] = gg;
                if (base + e < E) geo_c[base + e] = gg;
            }
        }
    }
    __syncthreads();

    // a1/m1 assembly: thread -> row = t>>2, col block = (t&3)*32
    // a1 = V'[r]+V[c]+ext3 ; m1 = M'[r]+M[c]+ext3 ; G1 chunks: {V 8B | M 8B} per col-quad
    {
        const int row = t >> 2, cq = t & 3;
        const int nr = node_s[row], nc = col_s[row];
        const float dist = dist_s[row], attr = attr_s[row], geo = geo_s[row];
        const ushort* pR = G1r + (size_t)nr * 256 + cq * 64;
        const ushort* pC = G1c + (size_t)nc * 256 + cq * 64;
        float p = 0.f;
#pragma unroll
        for (int k4 = 0; k4 < 8; ++k4) {
            const int c4 = cq * 32 + k4 * 4;
            const uint4 ru = *(const uint4*)(pR + k4 * 8);
            const uint4 cu = *(const uint4*)(pC + k4 * 8);
            const float2 av01 = up2(pkadd(ru.x, cu.x));
            const float2 av23 = up2(pkadd(ru.y, cu.y));
            const float2 mv01 = up2(pkadd(ru.z, cu.z));
            const float2 mv23 = up2(pkadd(ru.w, cu.w));
            const float4 e0 = *(const float4*)&ew_s[0][c4];
            const float4 e1 = *(const float4*)&ew_s[1][c4];
            const float4 e2 = *(const float4*)&ew_s[2][c4];
            const float4 f0 = *(const float4*)&ew_s[3][c4];
            const float4 f1 = *(const float4*)&ew_s[4][c4];
            const float4 f2 = *(const float4*)&ew_s[5][c4];
            const float4 w2 = *(const float4*)&ew_s[6][c4];
            const float a0 = av01.x + dist * e0.x + attr * e1.x + geo * e2.x;
            const float a1 = av01.y + dist * e0.y + attr * e1.y + geo * e2.y;
            const float a2 = av23.x + dist * e0.z + attr * e1.z + geo * e2.z;
            const float a3 = av23.y + dist * e0.w + attr * e1.w + geo * e2.w;
            p += siluf(a0) * w2.x + siluf(a1) * w2.y + siluf(a2) * w2.z + siluf(a3) * w2.w;
            const float m0 = siluf(mv01.x + dist * f0.x + attr * f1.x + geo * f2.x);
            const float m1v = siluf(mv01.y + dist * f0.y + attr * f1.y + geo * f2.y);
            const float m2 = siluf(mv23.x + dist * f0.z + attr * f1.z + geo * f2.z);
            const float m3 = siluf(mv23.y + dist * f0.w + attr * f1.w + geo * f2.w);
            *(uint2*)&m1_s[row][c4] = make_uint2(pkh(m0, m1v), pkh(m2, m3));
        }
        p += __shfl_xor(p, 1); p += __shfl_xor(p, 2);
        if (cq == 0) att_s[row] = sigmf(p + ba2f[0]) * em_s[row];
    }
    __syncthreads();   // m1 + att ready

    // GEMM3: msg = (m1@We2 + be2) * att
    f32x4 acc3[4][2] = {};
    {
        const half8* pB = (const half8*)(pack + (size_t)PE2 * 4096);
#pragma unroll
        for (int ks = 0; ks < 4; ++ks) {
            const half8 b0 = pB[(ks * 8 + w * 2 + 0) * 64 + lane];
            const half8 b1 = pB[(ks * 8 + w * 2 + 1) * 64 + lane];
#pragma unroll
            for (int mt = 0; mt < 4; ++mt) {
                const half8 a = *(const half8*)&m1_s[mt * 16 + l16][ks * 32 + quad * 8];
                acc3[mt][0] = MFMA16(a, b0, acc3[mt][0]);
                acc3[mt][1] = MFMA16(a, b1, acc3[mt][1]);
            }
        }
    }
    __syncthreads();   // all GEMM3 reads done -> f32 msg overlay

    // two passes: rows 0-31 then 32-63 (f32 msg fits [32][RS] exactly)
#pragma unroll
    for (int pass = 0; pass < 2; ++pass) {
#pragma unroll
        for (int mt = 0; mt < 2; ++mt)
#pragma unroll
            for (int reg = 0; reg < 4; ++reg) {
                const int row = (pass * 2 + mt) * 16 + quad * 4 + reg;
                const float av = att_s[row];
#pragma unroll
                for (int nt = 0; nt < 2; ++nt)
                    msg_s[row - pass * 32][w * 32 + nt * 16 + l16] =
                        (acc3[pass * 2 + mt][nt][reg] + b3[nt]) * av;
            }
        __syncthreads();
        {
            const int j = t & 127, s = t >> 7;
            const int r0 = pass * 32 + s * 16;
            float acc = 0.f;
            int rprev = node_s[r0];
#pragma unroll
            for (int k = 0; k < 16; ++k) {
                const int rn = node_s[r0 + k];
                if (rn != rprev) {
                    atomicAdd(&agg[(size_t)rprev * D + j], acc);
                    acc = 0.f; rprev = rn;
                }
                acc += msg_s[s * 16 + k][j];
            }
            atomicAdd(&agg[(size_t)rprev * D + j], acc);
        }
        __syncthreads();
    }
}

// ---------------- node2: MLP + residual + LN + silu; P,Q precompute ----------------
__global__ __launch_bounds__(256) void k_node2(
    const float* __restrict__ agg, float* hio,
    const ushort* __restrict__ pack,
    const float* __restrict__ bn2f,
    const float* __restrict__ ln_g, const float* __restrict__ ln_b,
    const float* __restrict__ bc1f,
    ushort* __restrict__ Ph, ushort* __restrict__ Qh, int N) {
    __shared__ ushort ag_s[64][RS];
    __shared__ float redS[2][64], redQ[2][64];
    const int t = threadIdx.x, lane = t & 63, wave = t >> 6;
    const int quad = lane >> 4, l16 = lane & 15;
    const int mh = wave >> 1, nh = wave & 1;
    const int base = blockIdx.x * 64;

#pragma unroll
    for (int q = 0; q < 8; ++q) {
        const int f = t + 256 * q;
        const int row = f >> 5, c4 = (f & 31) << 2;
        const int node = base + row;
        float4 v = make_float4(0.f, 0.f, 0.f, 0.f);
        if (node < N) v = *(const float4*)(agg + (size_t)node * D + c4);
        *(uint2*)&ag_s[row][c4] = make_uint2(pkh(v.x, v.y), pkh(v.z, v.w));
    }
    float bn2[4], lg[4], lb[4], bc1v[4];
#pragma unroll
    for (int nt = 0; nt < 4; ++nt) {
        const int col = nh * 64 + nt * 16 + l16;
        bn2[nt] = bn2f[col]; lg[nt] = ln_g[col]; lb[nt] = ln_b[col]; bc1v[nt] = bc1f[col];
    }
    __syncthreads();

    half8 aext = (half8)0;
    if (quad == 0) aext[0] = (__fp16)1.0f;

    f32x4 acc[2][4] = {};
    {
        const half8* pB = (const half8*)(pack + (size_t)PN1 * 4096);
#pragma unroll
        for (int ks = 0; ks < 5; ++ks) {
            half8 bfr[4];
#pragma unroll
            for (int nt = 0; nt < 4; ++nt) bfr[nt] = pB[(ks * 8 + nh * 4 + nt) * 64 + lane];
#pragma unroll
            for (int mt = 0; mt < 2; ++mt) {
                const half8 a = (ks < 4) ? *(const half8*)&ag_s[mh * 32 + mt * 16 + l16][ks * 32 + quad * 8]
                                         : aext;
#pragma unroll
                for (int nt = 0; nt < 4; ++nt) acc[mt][nt] = MFMA16(a, bfr[nt], acc[mt][nt]);
            }
        }
    }
    __syncthreads();
#pragma unroll
    for (int mt = 0; mt < 2; ++mt)
#pragma unroll
        for (int reg = 0; reg < 4; ++reg) {
            const int row = mh * 32 + mt * 16 + quad * 4 + reg;
#pragma unroll
            for (int nt = 0; nt < 4; ++nt)
                ag_s[row][nh * 64 + nt * 16 + l16] = f2hs(siluf(acc[mt][nt][reg]));
        }
    __syncthreads();

    {
        const half8* pB = (const half8*)(pack + (size_t)PN2 * 4096);
#pragma unroll
        for (int mt = 0; mt < 2; ++mt)
#pragma unroll
            for (int nt = 0; nt < 4; ++nt) acc[mt][nt] = (f32x4)0.0f;
#pragma unroll
        for (int ks = 0; ks < 4; ++ks) {
            half8 bfr[4];
#pragma unroll
            for (int nt = 0; nt < 4; ++nt) bfr[nt] = pB[(ks * 8 + nh * 4 + nt) * 64 + lane];
#pragma unroll
            for (int mt = 0; mt < 2; ++mt) {
                const half8 a = *(const half8*)&ag_s[mh * 32 + mt * 16 + l16][ks * 32 + quad * 8];
#pragma unroll
                for (int nt = 0; nt < 4; ++nt) acc[mt][nt] = MFMA16(a, bfr[nt], acc[mt][nt]);
            }
        }
    }
#pragma unroll
    for (int mt = 0; mt < 2; ++mt)
#pragma unroll
        for (int reg = 0; reg < 4; ++reg) {
            const int row = mh * 32 + mt * 16 + quad * 4 + reg;
            const int g = base + row;
            float s = 0.f, qq = 0.f;
#pragma unroll
            for (int nt = 0; nt < 4; ++nt) {
                const int col = nh * 64 + nt * 16 + l16;
                float v = acc[mt][nt][reg] + bn2[nt];
                if (g < N) v += hio[(size_t)g * D + col];
                acc[mt][nt][reg] = v;
                s += v; qq += v * v;
            }
            s += __shfl_xor(s, 1); s += __shfl_xor(s, 2); s += __shfl_xor(s, 4); s += __shfl_xor(s, 8);
            qq += __shfl_xor(qq, 1); qq += __shfl_xor(qq, 2); qq += __shfl_xor(qq, 4); qq += __shfl_xor(qq, 8);
            if (l16 == 0) { redS[nh][row] = s; redQ[nh][row] = qq; }
        }
    __syncthreads();

#pragma unroll
    for (int mt = 0; mt < 2; ++mt)
#pragma unroll
        for (int reg = 0; reg < 4; ++reg) {
            const int row = mh * 32 + mt * 16 + quad * 4 + reg;
            const int g = base + row;
            const float mu = (redS[0][row] + redS[1][row]) * (1.0f / D);
            const float var = (redQ[0][row] + redQ[1][row]) * (1.0f / D) - mu * mu;
            const float rstd = rsqrtf(var + 1e-5f);
#pragma unroll
            for (int nt = 0; nt < 4; ++nt) {
                const int col = nh * 64 + nt * 16 + l16;
                const float hn = (acc[mt][nt][reg] - mu) * rstd * lg[nt] + lb[nt];
                const float o = siluf(hn);
                ag_s[row][col] = f2hs(o);                     // hh2 f16 for P/Q K-loops
                if (g < N) hio[(size_t)g * D + col] = o;
            }
        }
    __syncthreads();

    // P = hh2@Wc1_top + bc1 (f16)
    {
        f32x4 a2[2][4] = {};
        const half8* pB = (const half8*)(pack + (size_t)PP * 4096);
#pragma unroll
        for (int ks = 0; ks < 4; ++ks) {
            half8 bfr[4];
#pragma unroll
            for (int nt = 0; nt < 4; ++nt) bfr[nt] = pB[(ks * 8 + nh * 4 + nt) * 64 + lane];
#pragma unroll
            for (int mt = 0; mt < 2; ++mt) {
                const half8 a = *(const half8*)&ag_s[mh * 32 + mt * 16 + l16][ks * 32 + quad * 8];
#pragma unroll
                for (int nt = 0; nt < 4; ++nt) a2[mt][nt] = MFMA16(a, bfr[nt], a2[mt][nt]);
            }
        }
#pragma unroll
        for (int mt = 0; mt < 2; ++mt)
#pragma unroll
            for (int reg = 0; reg < 4; ++reg) {
                const int g = base + mh * 32 + mt * 16 + quad * 4 + reg;
                if (g < N)
#pragma unroll
                    for (int nt = 0; nt < 4; ++nt)
                        Ph[(size_t)g * D + nh * 64 + nt * 16 + l16] = f2hs(a2[mt][nt][reg] + bc1v[nt]);
            }
    }
    // Q = hh2@Wc1_bot (f16)
    {
        f32x4 a2[2][4] = {};
        const half8* pB = (const half8*)(pack + (size_t)PQ * 4096);
#pragma unroll
        for (int ks = 0; ks < 4; ++ks) {
            half8 bfr[4];
#pragma unroll
            for (int nt = 0; nt < 4; ++nt) bfr[nt] = pB[(ks * 8 + nh * 4 + nt) * 64 + lane];
#pragma unroll
            for (int mt = 0; mt < 2; ++mt) {
                const half8 a = *(const half8*)&ag_s[mh * 32 + mt * 16 + l16][ks * 32 + quad * 8];
#pragma unroll
                for (int nt = 0; nt < 4; ++nt) a2[mt][nt] = MFMA16(a, bfr[nt], a2[mt][nt]);
            }
        }
#pragma unroll
        for (int mt = 0; mt < 2; ++mt)
#pragma unroll
            for (int reg = 0; reg < 4; ++reg) {
                const int g = base + mh * 32 + mt * 16 + quad * 4 + reg;
                if (g < N)
#pragma unroll
                    for (int nt = 0; nt < 4; ++nt)
                        Qh[(size_t)g * D + nh * 64 + nt * 16 + l16] = f2hs(a2[mt][nt][reg]);
            }
    }
}

// ---------------- edge phase 2: assemble c1, GEMM2, coord reduce ----------------
__global__ __launch_bounds__(256, 6) void k_edge2(
    const float4* __restrict__ rec, const float* __restrict__ geo_c,
    const ushort* __restrict__ Ph, const ushort* __restrict__ Qh,
    const ushort* __restrict__ pack,
    const float* __restrict__ Wc1,
    const float* __restrict__ bc2f, const float* __restrict__ Wc3f,
    float* __restrict__ aggx, int E) {
    __shared__ ushort c1_s[64][RS];
    __shared__ float ew_s[3][128];
    __shared__ float dist_s[64], attr_s[64], geo_s[64], tr_s[64];
    __shared__ float cdx_s[64], cdy_s[64], cdz_s[64];
    __shared__ int node_s[64], col_s[64];
    __shared__ float mp_s[4][64];

    const int t = threadIdx.x, lane = t & 63, w = t >> 6;
    const int quad = lane >> 4, l16 = lane & 15;
    const int base = blockIdx.x * 64;

    if (t < 64) {
        const int i = base + t;
        int r = 0, c = 0;
        float dist = 1.f, geo = 0.f, at = 0.f, emv = 0.f, cdx = 0.f, cdy = 0.f, cdz = 0.f;
        if (i < E) {
            const float4 ra = rec[2 * i + 0];
            const float4 rb = rec[2 * i + 1];
            r = __float_as_int(ra.x); c = __float_as_int(ra.y);
            dist = ra.z; at = ra.w;
            emv = rb.x; cdx = rb.y; cdy = rb.z; cdz = rb.w;
            geo = geo_c[i];
        }
        node_s[t] = r; col_s[t] = c;
        dist_s[t] = dist; geo_s[t] = geo; attr_s[t] = at; tr_s[t] = emv;  // tr_s holds em
        cdx_s[t] = cdx; cdy_s[t] = cdy; cdz_s[t] = cdz;
    }
    for (int i = t; i < 384; i += 256) {
        const int r = i >> 7, c = i & 127;
        ew_s[r][c] = Wc1[(256 + r) * D + c];
    }
    float bc2[2], wc3[2];
#pragma unroll
    for (int nt = 0; nt < 2; ++nt) {
        const int col = w * 32 + nt * 16 + l16;
        bc2[nt] = bc2f[col]; wc3[nt] = Wc3f[col];
    }
    __syncthreads();

    // c1 assembly: c1 = silu(P[r] + Q[c] + ext3), ext rows from LDS
    {
        const int row = t >> 2, cq = t & 3;
        const int nr = node_s[row], nc = col_s[row];
        const float dist = dist_s[row], attr = attr_s[row], geo = geo_s[row];
        const ushort* pP = Ph + (size_t)nr * D + cq * 32;
        const ushort* pQ = Qh + (size_t)nc * D + cq * 32;
#pragma unroll
        for (int k4 = 0; k4 < 8; ++k4) {
            const int c4 = cq * 32 + k4 * 4;
            const uint2 pu = *(const uint2*)(pP + k4 * 4);
            const uint2 qu = *(const uint2*)(pQ + k4 * 4);
            const float2 s01 = up2(pkadd(pu.x, qu.x));
            const float2 s23 = up2(pkadd(pu.y, qu.y));
            const float4 e0 = *(const float4*)&ew_s[0][c4];
            const float4 e1 = *(const float4*)&ew_s[1][c4];
            const float4 e2 = *(const float4*)&ew_s[2][c4];
            const float c0 = siluf(s01.x + dist * e0.x + attr * e1.x + geo * e2.x);
            const float c1 = siluf(s01.y + dist * e0.y + attr * e1.y + geo * e2.y);
            const float c2 = siluf(s23.x + dist * e0.z + attr * e1.z + geo * e2.z);
            const float c3 = siluf(s23.y + dist * e0.w + attr * e1.w + geo * e2.w);
            *(uint2*)&c1_s[row][c4] = make_uint2(pkh(c0, c1), pkh(c2, c3));
        }
    }
    __syncthreads();

    // GEMM2: c2 = silu(c1@Wc2 + bc2); m-partials over this wave's cols
    {
        f32x4 acc[4][2] = {};
        const half8* pB = (const half8*)(pack + (size_t)PC2 * 4096);
#pragma unroll
        for (int ks = 0; ks < 4; ++ks) {
            const half8 b0 = pB[(ks * 8 + w * 2 + 0) * 64 + lane];
            const half8 b1 = pB[(ks * 8 + w * 2 + 1) * 64 + lane];
#pragma unroll
            for (int mt = 0; mt < 4; ++mt) {
                const half8 a = *(const half8*)&c1_s[mt * 16 + l16][ks * 32 + quad * 8];
                acc[mt][0] = MFMA16(a, b0, acc[mt][0]);
                acc[mt][1] = MFMA16(a, b1, acc[mt][1]);
            }
        }
#pragma unroll
        for (int mt = 0; mt < 4; ++mt)
#pragma unroll
            for (int reg = 0; reg < 4; ++reg) {
                float p = siluf(acc[mt][0][reg] + bc2[0]) * wc3[0]
                        + siluf(acc[mt][1][reg] + bc2[1]) * wc3[1];
                p += __shfl_xor(p, 1); p += __shfl_xor(p, 2); p += __shfl_xor(p, 4); p += __shfl_xor(p, 8);
                if (l16 == 0) mp_s[w][mt * 16 + quad * 4 + reg] = p;
            }
    }
    __syncthreads();

    if (t < 64) {
        const float m = mp_s[0][t] + mp_s[1][t] + mp_s[2][t] + mp_s[3][t];
        tr_s[t] = m * tr_s[t];   // m * em
        if (base + t >= E) tr_s[t] = 0.f;
    }
    __syncthreads();

    // segmented per-block reduce of trans into aggx (3 lanes x,y,z; two 32-row halves)
    {
        const int h = t >> 7, tt = t & 127;
        if (tt < 3) {
            const float* cds = (tt == 0) ? cdx_s : (tt == 1) ? cdy_s : cdz_s;
            float acc = 0.f;
            int rprev = node_s[h * 32];
#pragma unroll
            for (int k = 0; k < 32; ++k) {
                const int row = h * 32 + k;
                const int rn = node_s[row];
                if (rn != rprev) {
                    atomicAdd(&aggx[rprev * 4 + tt], acc);
                    acc = 0.f; rprev = rn;
                }
                acc += cds[row] * tr_s[row];
            }
            atomicAdd(&aggx[rprev * 4 + tt], acc);
        }
    }
}

// ---------------- coord epilogue ----------------
__global__ void k_coord(const float* __restrict__ x, const float* __restrict__ nmask,
                        const float* __restrict__ aggx, float* __restrict__ out_x, int N) {
    const int idx = blockIdx.x * blockDim.x + threadIdx.x;
    if (idx >= N * 3) return;
    const int i = idx / 3, d = idx - i * 3;
    out_x[idx] = (x[idx] + aggx[i * 4 + d] * (1.0f / 100.0f)) * nmask[i];
}

extern "C" void kernel_launch(void* const* d_in, const int* in_sizes, int n_in,
                              void* d_out, int out_size, void* d_ws, size_t ws_size,
                              hipStream_t stream) {
    const float* h     = (const float*)d_in[0];
    const float* x     = (const float*)d_in[1];
    const int*   eidx  = (const int*)d_in[2];
    const float* nmask = (const float*)d_in[3];
    const float* emask = (const float*)d_in[4];
    const float* eattr = (const float*)d_in[5];
    const float* W_lin = (const float*)d_in[6];
    const float* b_lin = (const float*)d_in[7];
    const float* We1   = (const float*)d_in[8];
    const float* be1   = (const float*)d_in[9];
    const float* We2   = (const float*)d_in[10];
    const float* be2   = (const float*)d_in[11];
    const float* Wn1   = (const float*)d_in[12];
    const float* bn1   = (const float*)d_in[13];
    const float* Wn2   = (const float*)d_in[14];
    const float* bn2   = (const float*)d_in[15];
    const float* Wa1   = (const float*)d_in[16];
    const float* ba1   = (const float*)d_in[17];
    const float* Wa2   = (const float*)d_in[18];
    const float* ba2   = (const float*)d_in[19];
    const float* ln_g  = (const float*)d_in[20];
    const float* ln_b  = (const float*)d_in[21];
    const float* Wc1   = (const float*)d_in[22];
    const float* bc1   = (const float*)d_in[23];
    const float* Wc2   = (const float*)d_in[24];
    const float* bc2   = (const float*)d_in[25];
    const float* Wc3   = (const float*)d_in[26];

    const int N = in_sizes[0] / D;
    const int E = in_sizes[2] / 2;

    // ws layout (256-B aligned regions), ~60 MB
    char* wp = (char*)d_ws;
    auto take = [&](size_t bytes) -> void* {
        void* p = wp; wp += (bytes + 255) & ~(size_t)255; return p;
    };
    float*  agg   = (float*)take((size_t)N * D * 4);   // ┐ zeroed as one
    float*  aggx  = (float*)take((size_t)N * 4 * 4);   // │ contiguous
    int*    cnt   = (int*)take((size_t)N * 4);         // ┘ region
    int*    cur   = (int*)take((size_t)N * 4);
    float4* rec   = (float4*)take((size_t)E * 32);
    float*  geo_c = (float*)take((size_t)E * 4);
    ushort* hh1b  = (ushort*)take((size_t)N * D * 2);
    ushort* G1r   = (ushort*)take((size_t)N * 256 * 2);
    ushort* G1c   = (ushort*)take((size_t)N * 256 * 2);
    ushort* Ph    = (ushort*)take((size_t)N * D * 2);
    ushort* Qh    = (ushort*)take((size_t)N * D * 2);
    ushort* pack  = (ushort*)take((size_t)NPACK * 4096 * 2);

    float* out_h = (float*)d_out;          // doubles as hh fp32 storage
    float* out_x = out_h + (size_t)N * D;

    const int EB = (E + 63) / 64;
    const int NB = (N + 63) / 64;
    const long zn = ((char*)(cnt + N) - (char*)agg) / 4;   // agg..cnt contiguous

    k_zero<<<2048, 256, 0, stream>>>(agg, zn);
    k_packall<<<NPACK, 256, 0, stream>>>(W_lin, b_lin, Wa1, We1, We2,
                                         Wn1, bn1, Wn2, Wc1, Wc2, pack);
    k_hist<<<1024, 256, 0, stream>>>(eidx, cnt, E);
    k_scan<<<1, 1024, 0, stream>>>(cnt, cur, N);
    k_scatter_build<<<1024, 256, 0, stream>>>(eidx, x, eattr, emask, cur, rec, E);
    k_node_lin<<<NB, 256, 0, stream>>>(h, pack, out_h, hh1b, G1r, G1c, ba1, be1, N);
    k_edge1<<<EB, 256, 0, stream>>>(rec, hh1b, G1r, G1c, pack, Wa1, We1,
                                    Wa2, ba2, be2, agg, geo_c, E);
    k_node2<<<NB, 256, 0, stream>>>(agg, out_h, pack, bn2, ln_g, ln_b, bc1, Ph, Qh, N);
    k_edge2<<<EB, 256, 0, stream>>>(rec, geo_c, Ph, Qh, pack, Wc1, bc2, Wc3, aggx, E);
    k_coord<<<(N * 3 + 255) / 256, 256, 0, stream>>>(x, nmask, aggx, out_x, N);
}

// Round 11
// 443.410 us; speedup vs baseline: 1.5242x; 1.1088x over previous
//
#include <hip/hip_runtime.h>
#include <hip/hip_bf16.h>

// EquivariantBlock — Round 20.
// R19 post-mortem: G1 interleave NEUTRAL on VALU time (90us both) and negative
// on stalls/writes (edge1 140->167). Reverted. R15 = verified best (461us).
// R20 = exact R15 + manual 2-deep software pipeline in the gather loops:
// edge1 geo (uint4 pair), edge1 a1/m1 assembly (4x uint2), edge2 c1 assembly
// (2x uint2) — issue k4+1 loads before computing k4. Compiler scheduled these
// just-in-time (VGPR 40 of 85 budget, 30% no-issue); forcing load-ahead hides
// L2/L3 gather latency under the previous step's ~100 VALU cycles. +8-16 live
// regs -> VGPR ~56-64, under the 73-reg 7-block ceiling (no R14-style spill).

#define D 128
#define RS 136          // LDS row stride in fp16 units (128 + 8 pad; 272B rows)

typedef unsigned short ushort;
typedef __fp16 half8 __attribute__((ext_vector_type(8)));     // MFMA operand (V8h)
typedef __fp16 h16x2 __attribute__((ext_vector_type(2)));     // builtin boundary
typedef _Float16 f16x2 __attribute__((ext_vector_type(2)));   // packed math
typedef __attribute__((ext_vector_type(4))) float f32x4;

__device__ __forceinline__ float rcpf(float x) { return __builtin_amdgcn_rcpf(x); }
__device__ __forceinline__ float siluf(float x) { return x * rcpf(1.0f + __expf(-x)); }
__device__ __forceinline__ float sigmf(float x) { return rcpf(1.0f + __expf(-x)); }
__device__ __forceinline__ ushort f2hs(float f) {
    _Float16 h = (_Float16)f; ushort u; __builtin_memcpy(&u, &h, 2); return u;
}
__device__ __forceinline__ unsigned pkh(float lo, float hi) {
    auto h = __builtin_amdgcn_cvt_pkrtz(lo, hi);   // v_cvt_pkrtz_f16_f32
    unsigned u; __builtin_memcpy(&u, &h, 4); return u;
}
__device__ __forceinline__ unsigned pkadd(unsigned a, unsigned b) {  // packed f16 a+b
    f16x2 x, y; __builtin_memcpy(&x, &a, 4); __builtin_memcpy(&y, &b, 4);
    f16x2 d = x + y; unsigned r; __builtin_memcpy(&r, &d, 4); return r;
}
__device__ __forceinline__ float2 up2(unsigned u) {  // 2 f16 -> 2 f32
    f16x2 h; __builtin_memcpy(&h, &u, 4);
    return make_float2((float)h.x, (float)h.y);
}
__device__ __forceinline__ float fdot2f(f16x2 a, f16x2 b, float c) {
#if __has_builtin(__builtin_amdgcn_fdot2)
    h16x2 ah, bh;
    __builtin_memcpy(&ah, &a, 4); __builtin_memcpy(&bh, &b, 4);
    return __builtin_amdgcn_fdot2(ah, bh, c, false);
#else
    return c + (float)a.x * (float)b.x + (float)a.y * (float)b.y;
#endif
}
#define MFMA16(a, b, c) __builtin_amdgcn_mfma_f32_16x16x32_f16((a), (b), (c), 0, 0, 0)

// packed-weight block offsets (units of 4096 ushorts)
#define PWLIN 0     // W_lin + ext(b_lin)            [5]
#define PU    5     // Wa1[0:128]  (V' = hh@W1+ba1)  [4]
#define PV    9     // Wa1[128:256]                  [4]
#define PM    13    // We1[0:128]                    [4]
#define PE2   17    // We2                           [4]
#define PN1   21    // Wn1 + ext(bn1)                [5]
#define PN2   26    // Wn2                           [4]
#define PP    30    // Wc1[0:128]                    [4]
#define PQ    34    // Wc1[128:256]                  [4]
#define PC2   38    // Wc2                           [4]
#define NPACK 42

// ---------------- zero scratch ----------------
__global__ void k_zero(float* __restrict__ p, long n) {
    long i = (long)blockIdx.x * blockDim.x + threadIdx.x;
    long stride = (long)gridDim.x * blockDim.x;
    for (; i < n; i += stride) p[i] = 0.0f;
}

// ---------------- CSR build ----------------
__global__ void k_hist(const int* __restrict__ eidx, int* __restrict__ cnt, int E) {
    int i = blockIdx.x * blockDim.x + threadIdx.x;
    const int stride = gridDim.x * blockDim.x;
    for (; i < E; i += stride) atomicAdd(&cnt[eidx[i]], 1);
}

__global__ __launch_bounds__(1024) void k_scan(const int* __restrict__ cnt,
                                               int* __restrict__ cur, int N) {
    __shared__ int part[1024];
    const int t = threadIdx.x;
    const int chunk = (N + 1023) / 1024;
    int s = 0;
    for (int k = 0; k < chunk; ++k) {
        const int i = t * chunk + k;
        if (i < N) s += cnt[i];
    }
    part[t] = s;
    __syncthreads();
    for (int d = 1; d < 1024; d <<= 1) {
        const int v = (t >= d) ? part[t - d] : 0;
        __syncthreads();
        part[t] += v;
        __syncthreads();
    }
    int base = (t == 0) ? 0 : part[t - 1];
    for (int k = 0; k < chunk; ++k) {
        const int i = t * chunk + k;
        if (i < N) { cur[i] = base; base += cnt[i]; }
    }
}

// scatter + build CSR-ordered 32B AoS records: {r,c,dist,attr | em,cdx,cdy,cdz}
__global__ void k_scatter_build(
    const int* __restrict__ eidx, const float* __restrict__ x,
    const float* __restrict__ eattr, const float* __restrict__ emask,
    int* __restrict__ cur, float4* __restrict__ rec, int E) {
    int i = blockIdx.x * blockDim.x + threadIdx.x;
    const int stride = gridDim.x * blockDim.x;
    for (; i < E; i += stride) {
        const int r = eidx[i], c = eidx[E + i];
        const int p = atomicAdd(&cur[r], 1);
        const float dx = x[r * 3 + 0] - x[c * 3 + 0];
        const float dy = x[r * 3 + 1] - x[c * 3 + 1];
        const float dz = x[r * 3 + 2] - x[c * 3 + 2];
        const float dist = sqrtf(dx * dx + dy * dy + dz * dz + 1e-8f);
        const float inv = rcpf(dist + 1.0f);
        rec[2 * p + 0] = make_float4(__int_as_float(r), __int_as_float(c), dist, eattr[i]);
        rec[2 * p + 1] = make_float4(emask[i], dx * inv, dy * inv, dz * inv);
    }
}

// ---------------- fused weight pack (fp16) ----------------
__global__ __launch_bounds__(256) void k_packall(
    const float* __restrict__ W_lin, const float* __restrict__ b_lin,
    const float* __restrict__ Wa1,
    const float* __restrict__ We1,
    const float* __restrict__ We2,
    const float* __restrict__ Wn1, const float* __restrict__ bn1,
    const float* __restrict__ Wn2,
    const float* __restrict__ Wc1,
    const float* __restrict__ Wc2,
    ushort* __restrict__ pack) {
    const int b = blockIdx.x, t = threadIdx.x;
    const float* W = nullptr; const float* bias = nullptr;
    int kbase = 0, fold = 0, ext = 0, nW = 0;
    if (b < 5)       { W = W_lin; bias = b_lin; if (b == 4) { ext = 1; nW = 0; } else kbase = b * 32; }
    else if (b < 9)  { W = Wa1; kbase = (b - 5) * 32; }                    // PU (top half)
    else if (b < 13) { W = Wa1; kbase = 128 + (b - 9) * 32; }              // PV
    else if (b < 17) { W = We1; kbase = (b - 13) * 32; }                   // PM
    else if (b < 21) { W = We2; kbase = (b - 17) * 32; }                   // PE2
    else if (b < 26) { int k = b - 21; W = Wn1; bias = bn1; if (k == 4) { ext = 1; nW = 0; } else kbase = k * 32; }
    else if (b < 30) { W = Wn2; kbase = (b - 26) * 32; }                   // PN2
    else if (b < 34) { W = Wc1; kbase = (b - 30) * 32; }                   // PP
    else if (b < 38) { W = Wc1; kbase = 128 + (b - 34) * 32; }             // PQ
    else             { W = Wc2; kbase = (b - 38) * 32; }                   // PC2
    ushort* dst = pack + (size_t)b * 4096;
#pragma unroll
    for (int i = 0; i < 16; ++i) {
        const int e = t + 256 * i;
        const int j = e & 7, lane = (e >> 3) & 63, nt = e >> 9;
        const int kl = (lane >> 4) * 8 + j;
        const int n = nt * 16 + (lane & 15);
        float v;
        if (!ext) {
            v = W[(kbase + kl) * D + n];
            if (fold) v += W[(kbase + kl + 128) * D + n];
        } else {
            v = (kl < nW) ? W[(kbase + kl) * D + n] : (kl == nW ? bias[n] : 0.0f);
        }
        dst[e] = f2hs(v);
    }
}

// ---------------- node_lin: hh = h @ W_lin + b; V',V,M',M per-node precompute ----------------
__global__ __launch_bounds__(256) void k_node_lin(
    const float* __restrict__ h, const ushort* __restrict__ pack,
    float* __restrict__ hh, ushort* __restrict__ hh1b,
    ushort* __restrict__ Vp, ushort* __restrict__ Vh,
    ushort* __restrict__ Mp, ushort* __restrict__ Mh,
    const float* __restrict__ ba1f, const float* __restrict__ be1f, int N) {
    __shared__ ushort hs[64][RS];
    const int t = threadIdx.x, lane = t & 63, wave = t >> 6;
    const int quad = lane >> 4, l16 = lane & 15;
    const int mh = wave >> 1, nh = wave & 1;
    const int base = blockIdx.x * 64;

#pragma unroll
    for (int q = 0; q < 8; ++q) {
        const int f = t + 256 * q;
        const int row = f >> 5, c4 = (f & 31) << 2;
        const int node = base + row;
        float4 v = make_float4(0.f, 0.f, 0.f, 0.f);
        if (node < N) v = *(const float4*)(h + (size_t)node * D + c4);
        *(uint2*)&hs[row][c4] = make_uint2(pkh(v.x, v.y), pkh(v.z, v.w));
    }
    float ba1v[4], be1v[4];
#pragma unroll
    for (int nt = 0; nt < 4; ++nt) {
        const int col = nh * 64 + nt * 16 + l16;
        ba1v[nt] = ba1f[col]; be1v[nt] = be1f[col];
    }
    __syncthreads();

    half8 aext = (half8)0;
    if (quad == 0) aext[0] = (__fp16)1.0f;

    f32x4 acc[2][4] = {};
    {
        const half8* pB = (const half8*)(pack + (size_t)PWLIN * 4096);
#pragma unroll
        for (int ks = 0; ks < 5; ++ks) {
            half8 bfr[4];
#pragma unroll
            for (int nt = 0; nt < 4; ++nt) bfr[nt] = pB[(ks * 8 + nh * 4 + nt) * 64 + lane];
#pragma unroll
            for (int mt = 0; mt < 2; ++mt) {
                const half8 a = (ks < 4) ? *(const half8*)&hs[mh * 32 + mt * 16 + l16][ks * 32 + quad * 8]
                                         : aext;
#pragma unroll
                for (int nt = 0; nt < 4; ++nt) acc[mt][nt] = MFMA16(a, bfr[nt], acc[mt][nt]);
            }
        }
    }
    __syncthreads();   // all hs reads done before overwrite
    // store hh (f32 out + f16) and overwrite hs with hh f16 for the precompute K-loops
#pragma unroll
    for (int mt = 0; mt < 2; ++mt)
#pragma unroll
        for (int reg = 0; reg < 4; ++reg) {
            const int row = mh * 32 + mt * 16 + quad * 4 + reg;
            const int g = base + row;
#pragma unroll
            for (int nt = 0; nt < 4; ++nt) {
                const int col = nh * 64 + nt * 16 + l16;
                const float v = acc[mt][nt][reg];
                const ushort hv = f2hs(v);
                hs[row][col] = hv;
                if (g < N) {
                    hh[(size_t)g * D + col] = v;
                    hh1b[(size_t)g * D + col] = hv;
                }
            }
        }
    __syncthreads();

    // V' = hh@Wa1_top + ba1 (f16)
    {
        f32x4 a2[2][4] = {};
        const half8* pB = (const half8*)(pack + (size_t)PU * 4096);
#pragma unroll
        for (int ks = 0; ks < 4; ++ks) {
            half8 bfr[4];
#pragma unroll
            for (int nt = 0; nt < 4; ++nt) bfr[nt] = pB[(ks * 8 + nh * 4 + nt) * 64 + lane];
#pragma unroll
            for (int mt = 0; mt < 2; ++mt) {
                const half8 a = *(const half8*)&hs[mh * 32 + mt * 16 + l16][ks * 32 + quad * 8];
#pragma unroll
                for (int nt = 0; nt < 4; ++nt) a2[mt][nt] = MFMA16(a, bfr[nt], a2[mt][nt]);
            }
        }
#pragma unroll
        for (int mt = 0; mt < 2; ++mt)
#pragma unroll
            for (int reg = 0; reg < 4; ++reg) {
                const int g = base + mh * 32 + mt * 16 + quad * 4 + reg;
                if (g < N)
#pragma unroll
                    for (int nt = 0; nt < 4; ++nt)
                        Vp[(size_t)g * D + nh * 64 + nt * 16 + l16] = f2hs(a2[mt][nt][reg] + ba1v[nt]);
            }
    }
    // V = hh@Wa1_bot (f16)
    {
        f32x4 a2[2][4] = {};
        const half8* pB = (const half8*)(pack + (size_t)PV * 4096);
#pragma unroll
        for (int ks = 0; ks < 4; ++ks) {
            half8 bfr[4];
#pragma unroll
            for (int nt = 0; nt < 4; ++nt) bfr[nt] = pB[(ks * 8 + nh * 4 + nt) * 64 + lane];
#pragma unroll
            for (int mt = 0; mt < 2; ++mt) {
                const half8 a = *(const half8*)&hs[mh * 32 + mt * 16 + l16][ks * 32 + quad * 8];
#pragma unroll
                for (int nt = 0; nt < 4; ++nt) a2[mt][nt] = MFMA16(a, bfr[nt], a2[mt][nt]);
            }
        }
#pragma unroll
        for (int mt = 0; mt < 2; ++mt)
#pragma unroll
            for (int reg = 0; reg < 4; ++reg) {
                const int g = base + mh * 32 + mt * 16 + quad * 4 + reg;
                if (g < N)
#pragma unroll
                    for (int nt = 0; nt < 4; ++nt)
                        Vh[(size_t)g * D + nh * 64 + nt * 16 + l16] = f2hs(a2[mt][nt][reg]);
            }
    }
    // M = hh@We1_top (f16); M' = be1 - M (f16)
    {
        f32x4 a2[2][4] = {};
        const half8* pB = (const half8*)(pack + (size_t)PM * 4096);
#pragma unroll
        for (int ks = 0; ks < 4; ++ks) {
            half8 bfr[4];
#pragma unroll
            for (int nt = 0; nt < 4; ++nt) bfr[nt] = pB[(ks * 8 + nh * 4 + nt) * 64 + lane];
#pragma unroll
            for (int mt = 0; mt < 2; ++mt) {
                const half8 a = *(const half8*)&hs[mh * 32 + mt * 16 + l16][ks * 32 + quad * 8];
#pragma unroll
                for (int nt = 0; nt < 4; ++nt) a2[mt][nt] = MFMA16(a, bfr[nt], a2[mt][nt]);
            }
        }
#pragma unroll
        for (int mt = 0; mt < 2; ++mt)
#pragma unroll
            for (int reg = 0; reg < 4; ++reg) {
                const int g = base + mh * 32 + mt * 16 + quad * 4 + reg;
                if (g < N)
#pragma unroll
                    for (int nt = 0; nt < 4; ++nt) {
                        const int col = nh * 64 + nt * 16 + l16;
                        const float v = a2[mt][nt][reg];
                        Mh[(size_t)g * D + col] = f2hs(v);
                        Mp[(size_t)g * D + col] = f2hs(be1v[nt] - v);
                    }
            }
    }
}

// ---------------- edge phase 1: gather-assemble a1/m1 (pipelined), GEMM3, segmented reduce ----------------
__global__ __launch_bounds__(256, 6) void k_edge1(
    const float4* __restrict__ rec,
    const ushort* __restrict__ hh1b,
    const ushort* __restrict__ Vp, const ushort* __restrict__ Vh,
    const ushort* __restrict__ Mp, const ushort* __restrict__ Mh,
    const ushort* __restrict__ pack,
    const float* __restrict__ Wa1, const float* __restrict__ We1,
    const float* __restrict__ Wa2f, const float* __restrict__ ba2f,
    const float* __restrict__ be2f,
    float* __restrict__ agg, float* __restrict__ geo_c, int E) {
    __shared__ ushort m1_s[64][RS];      // 17408B: m1 f16 tile; msg f32 overlay [32][RS]
    __shared__ float ew_s[7][128];       // rows: Wa1e0..2, We1e0..2, Wa2
    __shared__ float dist_s[64], attr_s[64], geo_s[64], att_s[64], em_s[64];
    __shared__ int node_s[64], col_s[64];

    float (*msg_s)[RS] = (float(*)[RS])&m1_s[0][0];   // 32*136*4 = 17408 exact

    const int t = threadIdx.x, lane = t & 63, w = t >> 6;
    const int quad = lane >> 4, l16 = lane & 15;
    const int base = blockIdx.x * 64;

    if (t < 64) {
        const int i = base + t;
        int r = 0, c = 0; float dist = 0.f, at = 0.f, emv = 0.f;
        if (i < E) {
            const float4 ra = rec[2 * i + 0];
            const float4 rb = rec[2 * i + 1];
            r = __float_as_int(ra.x); c = __float_as_int(ra.y);
            dist = ra.z; at = ra.w; emv = rb.x;
        }
        node_s[t] = r; col_s[t] = c;
        dist_s[t] = dist; attr_s[t] = at; em_s[t] = emv;
    }
    // ext-weight preload: 7 x 128 f32 (Wa1 ext rows, We1 ext rows, Wa2)
    for (int i = t; i < 896; i += 256) {
        const int r = i >> 7, c = i & 127;
        float v;
        if (r < 3)      v = Wa1[(256 + r) * D + c];
        else if (r < 6) v = We1[(128 + (r - 3)) * D + c];
        else            v = Wa2f[c];
        ew_s[r][c] = v;
    }
    float b3[2];
#pragma unroll
    for (int nt = 0; nt < 2; ++nt) b3[nt] = be2f[w * 32 + nt * 16 + l16];
    __syncthreads();

    // geo = ||hh1[r] - hh1[c]|| via packed f16 diff + fdot2 (2-deep prefetch)
    {
        const int g = t >> 4;
        uint4 vr = *(const uint4*)(hh1b + (size_t)node_s[g * 4] * D + l16 * 8);
        uint4 vc = *(const uint4*)(hh1b + (size_t)col_s[g * 4] * D + l16 * 8);
#pragma unroll
        for (int it = 0; it < 4; ++it) {
            const int e = g * 4 + it;
            uint4 vr_n, vc_n;
            if (it < 3) {
                vr_n = *(const uint4*)(hh1b + (size_t)node_s[e + 1] * D + l16 * 8);
                vc_n = *(const uint4*)(hh1b + (size_t)col_s[e + 1] * D + l16 * 8);
            }
            const unsigned* pr = (const unsigned*)&vr;
            const unsigned* pc = (const unsigned*)&vc;
            float s = 0.f;
#pragma unroll
            for (int q = 0; q < 4; ++q) {
                f16x2 hr2, hc2;
                __builtin_memcpy(&hr2, &pr[q], 4);
                __builtin_memcpy(&hc2, &pc[q], 4);
                const f16x2 d2 = hc2 - hr2;
                s = fdot2f(d2, d2, s);
            }
            s += __shfl_xor(s, 1); s += __shfl_xor(s, 2); s += __shfl_xor(s, 4); s += __shfl_xor(s, 8);
            if (l16 == 0) {
                const float gg = sqrtf(s + 1e-8f);
                geo_s[e] = gg;
                if (base + e < E) geo_c[base + e] = gg;
            }
            if (it < 3) { vr = vr_n; vc = vc_n; }
        }
    }
    __syncthreads();

    // a1/m1 assembly: thread -> row = t>>2, col block = (t&3)*32 (2-deep prefetch)
    // a1 = V'[r]+V[c]+ext3 ; m1 = M'[r]+M[c]+ext3 (ext weights from LDS)
    {
        const int row = t >> 2, cq = t & 3;
        const int nr = node_s[row], nc = col_s[row];
        const float dist = dist_s[row], attr = attr_s[row], geo = geo_s[row];
        const ushort* pVr = Vp + (size_t)nr * D + cq * 32;
        const ushort* pVc = Vh + (size_t)nc * D + cq * 32;
        const ushort* pMr = Mp + (size_t)nr * D + cq * 32;
        const ushort* pMc = Mh + (size_t)nc * D + cq * 32;
        float p = 0.f;
        uint2 vru = *(const uint2*)(pVr);
        uint2 vcu = *(const uint2*)(pVc);
        uint2 mru = *(const uint2*)(pMr);
        uint2 mcu = *(const uint2*)(pMc);
#pragma unroll
        for (int k4 = 0; k4 < 8; ++k4) {
            uint2 vru_n, vcu_n, mru_n, mcu_n;
            if (k4 < 7) {
                vru_n = *(const uint2*)(pVr + (k4 + 1) * 4);
                vcu_n = *(const uint2*)(pVc + (k4 + 1) * 4);
                mru_n = *(const uint2*)(pMr + (k4 + 1) * 4);
                mcu_n = *(const uint2*)(pMc + (k4 + 1) * 4);
            }
            const int c4 = cq * 32 + k4 * 4;
            const float2 av01 = up2(pkadd(vru.x, vcu.x));
            const float2 av23 = up2(pkadd(vru.y, vcu.y));
            const float2 mv01 = up2(pkadd(mru.x, mcu.x));
            const float2 mv23 = up2(pkadd(mru.y, mcu.y));
            const float4 e0 = *(const float4*)&ew_s[0][c4];
            const float4 e1 = *(const float4*)&ew_s[1][c4];
            const float4 e2 = *(const float4*)&ew_s[2][c4];
            const float4 f0 = *(const float4*)&ew_s[3][c4];
            const float4 f1 = *(const float4*)&ew_s[4][c4];
            const float4 f2 = *(const float4*)&ew_s[5][c4];
            const float4 w2 = *(const float4*)&ew_s[6][c4];
            const float a0 = av01.x + dist * e0.x + attr * e1.x + geo * e2.x;
            const float a1 = av01.y + dist * e0.y + attr * e1.y + geo * e2.y;
            const float a2 = av23.x + dist * e0.z + attr * e1.z + geo * e2.z;
            const float a3 = av23.y + dist * e0.w + attr * e1.w + geo * e2.w;
            p += siluf(a0) * w2.x + siluf(a1) * w2.y + siluf(a2) * w2.z + siluf(a3) * w2.w;
            const float m0 = siluf(mv01.x + dist * f0.x + attr * f1.x + geo * f2.x);
            const float m1v = siluf(mv01.y + dist * f0.y + attr * f1.y + geo * f2.y);
            const float m2 = siluf(mv23.x + dist * f0.z + attr * f1.z + geo * f2.z);
            const float m3 = siluf(mv23.y + dist * f0.w + attr * f1.w + geo * f2.w);
            *(uint2*)&m1_s[row][c4] = make_uint2(pkh(m0, m1v), pkh(m2, m3));
            if (k4 < 7) { vru = vru_n; vcu = vcu_n; mru = mru_n; mcu = mcu_n; }
        }
        p += __shfl_xor(p, 1); p += __shfl_xor(p, 2);
        if (cq == 0) att_s[row] = sigmf(p + ba2f[0]) * em_s[row];
    }
    __syncthreads();   // m1 + att ready

    // GEMM3: msg = (m1@We2 + be2) * att
    f32x4 acc3[4][2] = {};
    {
        const half8* pB = (const half8*)(pack + (size_t)PE2 * 4096);
#pragma unroll
        for (int ks = 0; ks < 4; ++ks) {
            const half8 b0 = pB[(ks * 8 + w * 2 + 0) * 64 + lane];
            const half8 b1 = pB[(ks * 8 + w * 2 + 1) * 64 + lane];
#pragma unroll
            for (int mt = 0; mt < 4; ++mt) {
                const half8 a = *(const half8*)&m1_s[mt * 16 + l16][ks * 32 + quad * 8];
                acc3[mt][0] = MFMA16(a, b0, acc3[mt][0]);
                acc3[mt][1] = MFMA16(a, b1, acc3[mt][1]);
            }
        }
    }
    __syncthreads();   // all GEMM3 reads done -> f32 msg overlay

    // two passes: rows 0-31 then 32-63 (f32 msg fits [32][RS] exactly)
#pragma unroll
    for (int pass = 0; pass < 2; ++pass) {
#pragma unroll
        for (int mt = 0; mt < 2; ++mt)
#pragma unroll
            for (int reg = 0; reg < 4; ++reg) {
                const int row = (pass * 2 + mt) * 16 + quad * 4 + reg;
                const float av = att_s[row];
#pragma unroll
                for (int nt = 0; nt < 2; ++nt)
                    msg_s[row - pass * 32][w * 32 + nt * 16 + l16] =
                        (acc3[pass * 2 + mt][nt][reg] + b3[nt]) * av;
            }
        __syncthreads();
        {
            const int j = t & 127, s = t >> 7;
            const int r0 = pass * 32 + s * 16;
            float acc = 0.f;
            int rprev = node_s[r0];
#pragma unroll
            for (int k = 0; k < 16; ++k) {
                const int rn = node_s[r0 + k];
                if (rn != rprev) {
                    atomicAdd(&agg[(size_t)rprev * D + j], acc);
                    acc = 0.f; rprev = rn;
                }
                acc += msg_s[s * 16 + k][j];
            }
            atomicAdd(&agg[(size_t)rprev * D + j], acc);
        }
        __syncthreads();
    }
}

// ---------------- node2: MLP + residual + LN + silu; P,Q precompute ----------------
__global__ __launch_bounds__(256) void k_node2(
    const float* __restrict__ agg, float* hio,
    const ushort* __restrict__ pack,
    const float* __restrict__ bn2f,
    const float* __restrict__ ln_g, const float* __restrict__ ln_b,
    const float* __restrict__ bc1f,
    ushort* __restrict__ Ph, ushort* __restrict__ Qh, int N) {
    __shared__ ushort ag_s[64][RS];
    __shared__ float redS[2][64], redQ[2][64];
    const int t = threadIdx.x, lane = t & 63, wave = t >> 6;
    const int quad = lane >> 4, l16 = lane & 15;
    const int mh = wave >> 1, nh = wave & 1;
    const int base = blockIdx.x * 64;

#pragma unroll
    for (int q = 0; q < 8; ++q) {
        const int f = t + 256 * q;
        const int row = f >> 5, c4 = (f & 31) << 2;
        const int node = base + row;
        float4 v = make_float4(0.f, 0.f, 0.f, 0.f);
        if (node < N) v = *(const float4*)(agg + (size_t)node * D + c4);
        *(uint2*)&ag_s[row][c4] = make_uint2(pkh(v.x, v.y), pkh(v.z, v.w));
    }
    float bn2[4], lg[4], lb[4], bc1v[4];
#pragma unroll
    for (int nt = 0; nt < 4; ++nt) {
        const int col = nh * 64 + nt * 16 + l16;
        bn2[nt] = bn2f[col]; lg[nt] = ln_g[col]; lb[nt] = ln_b[col]; bc1v[nt] = bc1f[col];
    }
    __syncthreads();

    half8 aext = (half8)0;
    if (quad == 0) aext[0] = (__fp16)1.0f;

    f32x4 acc[2][4] = {};
    {
        const half8* pB = (const half8*)(pack + (size_t)PN1 * 4096);
#pragma unroll
        for (int ks = 0; ks < 5; ++ks) {
            half8 bfr[4];
#pragma unroll
            for (int nt = 0; nt < 4; ++nt) bfr[nt] = pB[(ks * 8 + nh * 4 + nt) * 64 + lane];
#pragma unroll
            for (int mt = 0; mt < 2; ++mt) {
                const half8 a = (ks < 4) ? *(const half8*)&ag_s[mh * 32 + mt * 16 + l16][ks * 32 + quad * 8]
                                         : aext;
#pragma unroll
                for (int nt = 0; nt < 4; ++nt) acc[mt][nt] = MFMA16(a, bfr[nt], acc[mt][nt]);
            }
        }
    }
    __syncthreads();
#pragma unroll
    for (int mt = 0; mt < 2; ++mt)
#pragma unroll
        for (int reg = 0; reg < 4; ++reg) {
            const int row = mh * 32 + mt * 16 + quad * 4 + reg;
#pragma unroll
            for (int nt = 0; nt < 4; ++nt)
                ag_s[row][nh * 64 + nt * 16 + l16] = f2hs(siluf(acc[mt][nt][reg]));
        }
    __syncthreads();

    {
        const half8* pB = (const half8*)(pack + (size_t)PN2 * 4096);
#pragma unroll
        for (int mt = 0; mt < 2; ++mt)
#pragma unroll
            for (int nt = 0; nt < 4; ++nt) acc[mt][nt] = (f32x4)0.0f;
#pragma unroll
        for (int ks = 0; ks < 4; ++ks) {
            half8 bfr[4];
#pragma unroll
            for (int nt = 0; nt < 4; ++nt) bfr[nt] = pB[(ks * 8 + nh * 4 + nt) * 64 + lane];
#pragma unroll
            for (int mt = 0; mt < 2; ++mt) {
                const half8 a = *(const half8*)&ag_s[mh * 32 + mt * 16 + l16][ks * 32 + quad * 8];
#pragma unroll
                for (int nt = 0; nt < 4; ++nt) acc[mt][nt] = MFMA16(a, bfr[nt], acc[mt][nt]);
            }
        }
    }
#pragma unroll
    for (int mt = 0; mt < 2; ++mt)
#pragma unroll
        for (int reg = 0; reg < 4; ++reg) {
            const int row = mh * 32 + mt * 16 + quad * 4 + reg;
            const int g = base + row;
            float s = 0.f, qq = 0.f;
#pragma unroll
            for (int nt = 0; nt < 4; ++nt) {
                const int col = nh * 64 + nt * 16 + l16;
                float v = acc[mt][nt][reg] + bn2[nt];
                if (g < N) v += hio[(size_t)g * D + col];
                acc[mt][nt][reg] = v;
                s += v; qq += v * v;
            }
            s += __shfl_xor(s, 1); s += __shfl_xor(s, 2); s += __shfl_xor(s, 4); s += __shfl_xor(s, 8);
            qq += __shfl_xor(qq, 1); qq += __shfl_xor(qq, 2); qq += __shfl_xor(qq, 4); qq += __shfl_xor(qq, 8);
            if (l16 == 0) { redS[nh][row] = s; redQ[nh][row] = qq; }
        }
    __syncthreads();

#pragma unroll
    for (int mt = 0; mt < 2; ++mt)
#pragma unroll
        for (int reg = 0; reg < 4; ++reg) {
            const int row = mh * 32 + mt * 16 + quad * 4 + reg;
            const int g = base + row;
            const float mu = (redS[0][row] + redS[1][row]) * (1.0f / D);
            const float var = (redQ[0][row] + redQ[1][row]) * (1.0f / D) - mu * mu;
            const float rstd = rsqrtf(var + 1e-5f);
#pragma unroll
            for (int nt = 0; nt < 4; ++nt) {
                const int col = nh * 64 + nt * 16 + l16;
                const float hn = (acc[mt][nt][reg] - mu) * rstd * lg[nt] + lb[nt];
                const float o = siluf(hn);
                ag_s[row][col] = f2hs(o);                     // hh2 f16 for P/Q K-loops
                if (g < N) hio[(size_t)g * D + col] = o;
            }
        }
    __syncthreads();

    // P = hh2@Wc1_top + bc1 (f16)
    {
        f32x4 a2[2][4] = {};
        const half8* pB = (const half8*)(pack + (size_t)PP * 4096);
#pragma unroll
        for (int ks = 0; ks < 4; ++ks) {
            half8 bfr[4];
#pragma unroll
            for (int nt = 0; nt < 4; ++nt) bfr[nt] = pB[(ks * 8 + nh * 4 + nt) * 64 + lane];
#pragma unroll
            for (int mt = 0; mt < 2; ++mt) {
                const half8 a = *(const half8*)&ag_s[mh * 32 + mt * 16 + l16][ks * 32 + quad * 8];
#pragma unroll
                for (int nt = 0; nt < 4; ++nt) a2[mt][nt] = MFMA16(a, bfr[nt], a2[mt][nt]);
            }
        }
#pragma unroll
        for (int mt = 0; mt < 2; ++mt)
#pragma unroll
            for (int reg = 0; reg < 4; ++reg) {
                const int g = base + mh * 32 + mt * 16 + quad * 4 + reg;
                if (g < N)
#pragma unroll
                    for (int nt = 0; nt < 4; ++nt)
                        Ph[(size_t)g * D + nh * 64 + nt * 16 + l16] = f2hs(a2[mt][nt][reg] + bc1v[nt]);
            }
    }
    // Q = hh2@Wc1_bot (f16)
    {
        f32x4 a2[2][4] = {};
        const half8* pB = (const half8*)(pack + (size_t)PQ * 4096);
#pragma unroll
        for (int ks = 0; ks < 4; ++ks) {
            half8 bfr[4];
#pragma unroll
            for (int nt = 0; nt < 4; ++nt) bfr[nt] = pB[(ks * 8 + nh * 4 + nt) * 64 + lane];
#pragma unroll
            for (int mt = 0; mt < 2; ++mt) {
                const half8 a = *(const half8*)&ag_s[mh * 32 + mt * 16 + l16][ks * 32 + quad * 8];
#pragma unroll
                for (int nt = 0; nt < 4; ++nt) a2[mt][nt] = MFMA16(a, bfr[nt], a2[mt][nt]);
            }
        }
#pragma unroll
        for (int mt = 0; mt < 2; ++mt)
#pragma unroll
            for (int reg = 0; reg < 4; ++reg) {
                const int g = base + mh * 32 + mt * 16 + quad * 4 + reg;
                if (g < N)
#pragma unroll
                    for (int nt = 0; nt < 4; ++nt)
                        Qh[(size_t)g * D + nh * 64 + nt * 16 + l16] = f2hs(a2[mt][nt][reg]);
            }
    }
}

// ---------------- edge phase 2: assemble c1 (pipelined), GEMM2, coord reduce ----------------
__global__ __launch_bounds__(256, 6) void k_edge2(
    const float4* __restrict__ rec, const float* __restrict__ geo_c,
    const ushort* __restrict__ Ph, const ushort* __restrict__ Qh,
    const ushort* __restrict__ pack,
    const float* __restrict__ Wc1,
    const float* __restrict__ bc2f, const float* __restrict__ Wc3f,
    float* __restrict__ aggx, int E) {
    __shared__ ushort c1_s[64][RS];
    __shared__ float ew_s[3][128];
    __shared__ float dist_s[64], attr_s[64], geo_s[64], tr_s[64];
    __shared__ float cdx_s[64], cdy_s[64], cdz_s[64];
    __shared__ int node_s[64], col_s[64];
    __shared__ float mp_s[4][64];

    const int t = threadIdx.x, lane = t & 63, w = t >> 6;
    const int quad = lane >> 4, l16 = lane & 15;
    const int base = blockIdx.x * 64;

    if (t < 64) {
        const int i = base + t;
        int r = 0, c = 0;
        float dist = 1.f, geo = 0.f, at = 0.f, emv = 0.f, cdx = 0.f, cdy = 0.f, cdz = 0.f;
        if (i < E) {
            const float4 ra = rec[2 * i + 0];
            const float4 rb = rec[2 * i + 1];
            r = __float_as_int(ra.x); c = __float_as_int(ra.y);
            dist = ra.z; at = ra.w;
            emv = rb.x; cdx = rb.y; cdy = rb.z; cdz = rb.w;
            geo = geo_c[i];
        }
        node_s[t] = r; col_s[t] = c;
        dist_s[t] = dist; geo_s[t] = geo; attr_s[t] = at; tr_s[t] = emv;  // tr_s holds em
        cdx_s[t] = cdx; cdy_s[t] = cdy; cdz_s[t] = cdz;
    }
    for (int i = t; i < 384; i += 256) {
        const int r = i >> 7, c = i & 127;
        ew_s[r][c] = Wc1[(256 + r) * D + c];
    }
    float bc2[2], wc3[2];
#pragma unroll
    for (int nt = 0; nt < 2; ++nt) {
        const int col = w * 32 + nt * 16 + l16;
        bc2[nt] = bc2f[col]; wc3[nt] = Wc3f[col];
    }
    __syncthreads();

    // c1 assembly: c1 = silu(P[r] + Q[c] + ext3), ext rows from LDS (2-deep prefetch)
    {
        const int row = t >> 2, cq = t & 3;
        const int nr = node_s[row], nc = col_s[row];
        const float dist = dist_s[row], attr = attr_s[row], geo = geo_s[row];
        const ushort* pP = Ph + (size_t)nr * D + cq * 32;
        const ushort* pQ = Qh + (size_t)nc * D + cq * 32;
        uint2 pu = *(const uint2*)(pP);
        uint2 qu = *(const uint2*)(pQ);
#pragma unroll
        for (int k4 = 0; k4 < 8; ++k4) {
            uint2 pu_n, qu_n;
            if (k4 < 7) {
                pu_n = *(const uint2*)(pP + (k4 + 1) * 4);
                qu_n = *(const uint2*)(pQ + (k4 + 1) * 4);
            }
            const int c4 = cq * 32 + k4 * 4;
            const float2 s01 = up2(pkadd(pu.x, qu.x));
            const float2 s23 = up2(pkadd(pu.y, qu.y));
            const float4 e0 = *(const float4*)&ew_s[0][c4];
            const float4 e1 = *(const float4*)&ew_s[1][c4];
            const float4 e2 = *(const float4*)&ew_s[2][c4];
            const float c0 = siluf(s01.x + dist * e0.x + attr * e1.x + geo * e2.x);
            const float c1 = siluf(s01.y + dist * e0.y + attr * e1.y + geo * e2.y);
            const float c2 = siluf(s23.x + dist * e0.z + attr * e1.z + geo * e2.z);
            const float c3 = siluf(s23.y + dist * e0.w + attr * e1.w + geo * e2.w);
            *(uint2*)&c1_s[row][c4] = make_uint2(pkh(c0, c1), pkh(c2, c3));
            if (k4 < 7) { pu = pu_n; qu = qu_n; }
        }
    }
    __syncthreads();

    // GEMM2: c2 = silu(c1@Wc2 + bc2); m-partials over this wave's cols
    {
        f32x4 acc[4][2] = {};
        const half8* pB = (const half8*)(pack + (size_t)PC2 * 4096);
#pragma unroll
        for (int ks = 0; ks < 4; ++ks) {
            const half8 b0 = pB[(ks * 8 + w * 2 + 0) * 64 + lane];
            const half8 b1 = pB[(ks * 8 + w * 2 + 1) * 64 + lane];
#pragma unroll
            for (int mt = 0; mt < 4; ++mt) {
                const half8 a = *(const half8*)&c1_s[mt * 16 + l16][ks * 32 + quad * 8];
                acc[mt][0] = MFMA16(a, b0, acc[mt][0]);
                acc[mt][1] = MFMA16(a, b1, acc[mt][1]);
            }
        }
#pragma unroll
        for (int mt = 0; mt < 4; ++mt)
#pragma unroll
            for (int reg = 0; reg < 4; ++reg) {
                float p = siluf(acc[mt][0][reg] + bc2[0]) * wc3[0]
                        + siluf(acc[mt][1][reg] + bc2[1]) * wc3[1];
                p += __shfl_xor(p, 1); p += __shfl_xor(p, 2); p += __shfl_xor(p, 4); p += __shfl_xor(p, 8);
                if (l16 == 0) mp_s[w][mt * 16 + quad * 4 + reg] = p;
            }
    }
    __syncthreads();

    if (t < 64) {
        const float m = mp_s[0][t] + mp_s[1][t] + mp_s[2][t] + mp_s[3][t];
        tr_s[t] = m * tr_s[t];   // m * em
        if (base + t >= E) tr_s[t] = 0.f;
    }
    __syncthreads();

    // segmented per-block reduce of trans into aggx (3 lanes x,y,z; two 32-row halves)
    {
        const int h = t >> 7, tt = t & 127;
        if (tt < 3) {
            const float* cds = (tt == 0) ? cdx_s : (tt == 1) ? cdy_s : cdz_s;
            float acc = 0.f;
            int rprev = node_s[h * 32];
#pragma unroll
            for (int k = 0; k < 32; ++k) {
                const int row = h * 32 + k;
                const int rn = node_s[row];
                if (rn != rprev) {
                    atomicAdd(&aggx[rprev * 4 + tt], acc);
                    acc = 0.f; rprev = rn;
                }
                acc += cds[row] * tr_s[row];
            }
            atomicAdd(&aggx[rprev * 4 + tt], acc);
        }
    }
}

// ---------------- coord epilogue ----------------
__global__ void k_coord(const float* __restrict__ x, const float* __restrict__ nmask,
                        const float* __restrict__ aggx, float* __restrict__ out_x, int N) {
    const int idx = blockIdx.x * blockDim.x + threadIdx.x;
    if (idx >= N * 3) return;
    const int i = idx / 3, d = idx - i * 3;
    out_x[idx] = (x[idx] + aggx[i * 4 + d] * (1.0f / 100.0f)) * nmask[i];
}

extern "C" void kernel_launch(void* const* d_in, const int* in_sizes, int n_in,
                              void* d_out, int out_size, void* d_ws, size_t ws_size,
                              hipStream_t stream) {
    const float* h     = (const float*)d_in[0];
    const float* x     = (const float*)d_in[1];
    const int*   eidx  = (const int*)d_in[2];
    const float* nmask = (const float*)d_in[3];
    const float* emask = (const float*)d_in[4];
    const float* eattr = (const float*)d_in[5];
    const float* W_lin = (const float*)d_in[6];
    const float* b_lin = (const float*)d_in[7];
    const float* We1   = (const float*)d_in[8];
    const float* be1   = (const float*)d_in[9];
    const float* We2   = (const float*)d_in[10];
    const float* be2   = (const float*)d_in[11];
    const float* Wn1   = (const float*)d_in[12];
    const float* bn1   = (const float*)d_in[13];
    const float* Wn2   = (const float*)d_in[14];
    const float* bn2   = (const float*)d_in[15];
    const float* Wa1   = (const float*)d_in[16];
    const float* ba1   = (const float*)d_in[17];
    const float* Wa2   = (const float*)d_in[18];
    const float* ba2   = (const float*)d_in[19];
    const float* ln_g  = (const float*)d_in[20];
    const float* ln_b  = (const float*)d_in[21];
    const float* Wc1   = (const float*)d_in[22];
    const float* bc1   = (const float*)d_in[23];
    const float* Wc2   = (const float*)d_in[24];
    const float* bc2   = (const float*)d_in[25];
    const float* Wc3   = (const float*)d_in[26];

    const int N = in_sizes[0] / D;
    const int E = in_sizes[2] / 2;

    // ws layout (256-B aligned regions), ~60 MB
    char* wp = (char*)d_ws;
    auto take = [&](size_t bytes) -> void* {
        void* p = wp; wp += (bytes + 255) & ~(size_t)255; return p;
    };
    float*  agg   = (float*)take((size_t)N * D * 4);   // ┐ zeroed as one
    float*  aggx  = (float*)take((size_t)N * 4 * 4);   // │ contiguous
    int*    cnt   = (int*)take((size_t)N * 4);         // ┘ region
    int*    cur   = (int*)take((size_t)N * 4);
    float4* rec   = (float4*)take((size_t)E * 32);
    float*  geo_c = (float*)take((size_t)E * 4);
    ushort* hh1b  = (ushort*)take((size_t)N * D * 2);
    ushort* Vp    = (ushort*)take((size_t)N * D * 2);
    ushort* Vh    = (ushort*)take((size_t)N * D * 2);
    ushort* Mp    = (ushort*)take((size_t)N * D * 2);
    ushort* Mh    = (ushort*)take((size_t)N * D * 2);
    ushort* Ph    = (ushort*)take((size_t)N * D * 2);
    ushort* Qh    = (ushort*)take((size_t)N * D * 2);
    ushort* pack  = (ushort*)take((size_t)NPACK * 4096 * 2);

    float* out_h = (float*)d_out;          // doubles as hh fp32 storage
    float* out_x = out_h + (size_t)N * D;

    const int EB = (E + 63) / 64;
    const int NB = (N + 63) / 64;
    const long zn = ((char*)(cnt + N) - (char*)agg) / 4;   // agg..cnt contiguous

    k_zero<<<2048, 256, 0, stream>>>(agg, zn);
    k_packall<<<NPACK, 256, 0, stream>>>(W_lin, b_lin, Wa1, We1, We2,
                                         Wn1, bn1, Wn2, Wc1, Wc2, pack);
    k_hist<<<1024, 256, 0, stream>>>(eidx, cnt, E);
    k_scan<<<1, 1024, 0, stream>>>(cnt, cur, N);
    k_scatter_build<<<1024, 256, 0, stream>>>(eidx, x, eattr, emask, cur, rec, E);
    k_node_lin<<<NB, 256, 0, stream>>>(h, pack, out_h, hh1b, Vp, Vh, Mp, Mh, ba1, be1, N);
    k_edge1<<<EB, 256, 0, stream>>>(rec, hh1b, Vp, Vh, Mp, Mh, pack, Wa1, We1,
                                    Wa2, ba2, be2, agg, geo_c, E);
    k_node2<<<NB, 256, 0, stream>>>(agg, out_h, pack, bn2, ln_g, ln_b, bc1, Ph, Qh, N);
    k_edge2<<<EB, 256, 0, stream>>>(rec, geo_c, Ph, Qh, pack, Wc1, bc2, Wc3, aggx, E);
    k_coord<<<(N * 3 + 255) / 256, 256, 0, stream>>>(x, nmask, aggx, out_x, N);
}